// Round 15
// baseline (237.268 us; speedup 1.0000x reference)
//
#include <hip/hip_runtime.h>
#include <stdint.h>

// Problem constants (fixed by the reference)
#define NQ 1024
#define NS 131072
#define DMM 2048
#define DCC 64
#define K_TOP 16
#define EPS_RES_F 1e-8f
#define EPS_SQRT_F 1e-12f
#define EPS_A 0.01f       // bf16 hi-only dot abs-error coeff (rigorous bound ~0.004)

#define NCH 128           // candidate chunks over N
#define CHR (NS / NCH)    // 1024 rows per chunk
#define OVCAP 65536       // global overflow list capacity (rare)
#define SLOTS 24          // per-(q,chunk) candidate slots
#define MTOT (NCH * SLOTS)        // 3072 entries per query
#define EPT (MTOT / 256)          // 12 entries per thread
#define SCAP 3328         // survivor capacity >= MTOT + ovf slack

typedef __attribute__((ext_vector_type(8))) short short8v;  // 8 x bf16
typedef __attribute__((ext_vector_type(4))) float f32x4;
typedef unsigned long long u64t;

__device__ __forceinline__ unsigned short f2bf(float x) {  // RNE f32->bf16
  unsigned u = __float_as_uint(x);
  unsigned r = (u + 0x7FFFu + ((u >> 16) & 1u)) >> 16;
  return (unsigned short)r;
}
// directed bf16 rounding for POSITIVE floats (bounds stay provable)
__device__ __forceinline__ unsigned bf16_down_pos(float x) {
  return __float_as_uint(x) >> 16;
}
__device__ __forceinline__ unsigned bf16_up_pos(float x) {
  const unsigned u = __float_as_uint(x);
  return (u >> 16) + ((u & 0xFFFFu) ? 1u : 0u);
}

__device__ __forceinline__ void gl_lds16(const void* g, void* l) {
  __builtin_amdgcn_global_load_lds(
      (const __attribute__((address_space(1))) unsigned int*)g,
      (__attribute__((address_space(3))) unsigned int*)l, 16, 0, 0);
}

// exact key chain — MUST stay bit-identical to sub_kernel's accumulation
__device__ __forceinline__ float exact_key(const float* __restrict__ stored,
                                           const float* qgl, float q2v,
                                           const float4* __restrict__ aux4, int n) {
  const float4* srow = reinterpret_cast<const float4*>(stored + (size_t)n * DCC);
  float a = 0.f;
#pragma unroll
  for (int kb = 0; kb < 16; ++kb) {
    const float4 qv = *reinterpret_cast<const float4*>(&qgl[4 * kb]);
    const float4 sv = srow[kb];
    a = fmaf(qv.w, sv.w, fmaf(qv.z, sv.z, fmaf(qv.y, sv.y, fmaf(qv.x, sv.x, a))));
  }
  const float4 av = aux4[n];
  const float d2 = fmaf(-2.f, a, q2v + av.x);
  return (fmaxf(d2, 0.f) + EPS_SQRT_F) * av.w;
}

// All lanes of a wave: find the bin containing 0-based `rank` in hist[256]
__device__ __forceinline__ void bin_rank256(const int* hist, int rank, int lane,
                                            int& binOut, int& baseOut, int& totalOut) {
  const int b0 = hist[4 * lane + 0], b1 = hist[4 * lane + 1];
  const int b2 = hist[4 * lane + 2], b3 = hist[4 * lane + 3];
  const int s01 = b0 + b1, s012 = s01 + b2;
  const int s = s012 + b3;
  int inc = s;
#pragma unroll
  for (int off = 1; off < 64; off <<= 1) {
    const int u = __shfl_up(inc, off);
    if (lane >= off) inc += u;
  }
  totalOut = __shfl(inc, 63);
  const int excl = inc - s;
  const bool has = (excl <= rank) && (rank < inc);
  const unsigned long long mask = __ballot(has);
  if (mask == 0ULL) { binOut = -1; baseOut = 0; return; }
  const int who = __ffsll((unsigned long long)mask) - 1;
  const int exclW = __shfl(excl, who);
  const int c0 = __shfl(b0, who);
  const int c01 = __shfl(s01, who);
  const int c012 = __shfl(s012, who);
  const int r = rank - exclW;
  int sub, base;
  if (r < c0) { sub = 0; base = 0; }
  else if (r < c01) { sub = 1; base = c0; }
  else if (r < c012) { sub = 2; base = c01; }
  else { sub = 3; base = c012; }
  binOut = 4 * who + sub;
  baseOut = exclW + base;
}

// ---------------------------------------------------------------- G = M M^T
__global__ __launch_bounds__(256) void g_kernel(const float* __restrict__ M,
                                                float* __restrict__ G) {
  __shared__ __align__(16) float Ml[64 * 66];
  const int t = threadIdx.x;
  for (int p = 0; p < 16; ++p) {
    int i = p * 256 + t;
    Ml[(i >> 6) * 66 + (i & 63)] = M[i];
  }
  __syncthreads();
  const int e = blockIdx.x * 256 + t;
  const int i = e >> 6, j = e & 63;
  float a = 0.f;
#pragma unroll
  for (int k = 0; k < 64; ++k) a = fmaf(Ml[i * 66 + k], Ml[j * 66 + k], a);
  G[e] = a;
}

// ---------------- qc = q W ; qG = qc G ; q2 = qc.qG ; qGh bf16 ; qe = eps*|qG|
// ROUND-9 KNOWN-GOOD VERSION, byte-for-byte. The qc summation order is
// ordering-critical (r11 failure), and BOTH restructurings tried (r10 2q/block,
// r14 float4 LDS reads) were ~10-20us SLOWER in the total. Do not touch.
__global__ __launch_bounds__(256) void q_kernel(
    const float* __restrict__ query, const float* __restrict__ W,
    const float* __restrict__ G, float* __restrict__ qGT,
    float* __restrict__ qGr, unsigned short* __restrict__ qGh,
    float* __restrict__ q2o, float* __restrict__ qeo) {
  __shared__ __align__(16) float qs[4][DMM];
  __shared__ float part[4][4][64];
  __shared__ float qc[4][64];
  const int t = threadIdx.x;
  const int qb = blockIdx.x * 4;
  {
    const float4* src = reinterpret_cast<const float4*>(query + (size_t)qb * DMM);
    float4* dst = reinterpret_cast<float4*>(&qs[0][0]);
#pragma unroll
    for (int r = 0; r < 8; ++r) dst[r * 256 + t] = src[r * 256 + t];
  }
  __syncthreads();
  const int c = t & 63, seg = t >> 6;
  float p0 = 0.f, p1 = 0.f, p2 = 0.f, p3 = 0.f;
  const int kbase = seg * 512;
  for (int ki = 0; ki < 512; ++ki) {
    const int k = kbase + ki;
    const float w = W[(size_t)k * 64 + c];
    p0 = fmaf(qs[0][k], w, p0);
    p1 = fmaf(qs[1][k], w, p1);
    p2 = fmaf(qs[2][k], w, p2);
    p3 = fmaf(qs[3][k], w, p3);
  }
  part[0][seg][c] = p0; part[1][seg][c] = p1;
  part[2][seg][c] = p2; part[3][seg][c] = p3;
  __syncthreads();
  {
    const int q = t >> 6, cc = t & 63;
    qc[q][cc] = part[q][0][cc] + part[q][1][cc] + part[q][2][cc] + part[q][3][cc];
  }
  __syncthreads();
  const int w = t >> 6, lane = t & 63;
  float g = 0.f;
  for (int j = 0; j < 64; ++j) g = fmaf(qc[w][j], G[j * 64 + lane], g);
  const int q = qb + w;
  qGT[(size_t)lane * NQ + q] = g;
  qGr[(size_t)q * DCC + lane] = g;
  qGh[(size_t)q * DCC + lane] = f2bf(g);
  float pr = qc[w][lane] * g;
  float pn = g * g;
#pragma unroll
  for (int off = 32; off; off >>= 1) {
    pr += __shfl_xor(pr, off);
    pn += __shfl_xor(pn, off);
  }
  if (lane == 0) {
    q2o[q] = pr;
    qeo[q] = EPS_A * sqrtf(pn);
  }
}

// ---- aux4[n] = { s2, h=(res+eps)^2/2, sn=|s|, ir2 } ; sh = bf16(stored rows)
// ROUND-9 KNOWN-GOOD VERSION (r14 ushort4 store variant was part of a +20us
// regression in the non-main pot; reverted).
__global__ __launch_bounds__(256) void s_kernel(
    const float* __restrict__ stored, const float* __restrict__ resil,
    const float* __restrict__ G, float4* __restrict__ aux4o,
    unsigned short* __restrict__ sho) {
  __shared__ __align__(16) float Gl[64 * 66];
  __shared__ __align__(16) float sst[64 * 64];
  __shared__ float part2[64 * 33];
  __shared__ float ps[64 * 33];
  const int t = threadIdx.x;
  const int nb = blockIdx.x * 64;
  for (int p = 0; p < 16; ++p) {
    int i = p * 256 + t;
    Gl[(i >> 6) * 66 + (i & 63)] = G[i];
  }
  {
    const float4* src = reinterpret_cast<const float4*>(stored + (size_t)nb * DCC);
    float4* dst = reinterpret_cast<float4*>(sst);
#pragma unroll
    for (int r = 0; r < 4; ++r) dst[r * 256 + t] = src[r * 256 + t];
  }
  __syncthreads();
  const int l = t & 31, tw = t >> 5;
  float acc0[8], acc1[8];
#pragma unroll
  for (int i = 0; i < 8; ++i) { acc0[i] = 0.f; acc1[i] = 0.f; }
  for (int kb = 0; kb < 16; ++kb) {
    const float2 ga0 = *reinterpret_cast<const float2*>(&Gl[(4 * kb + 0) * 66 + 2 * l]);
    const float2 ga1 = *reinterpret_cast<const float2*>(&Gl[(4 * kb + 1) * 66 + 2 * l]);
    const float2 ga2 = *reinterpret_cast<const float2*>(&Gl[(4 * kb + 2) * 66 + 2 * l]);
    const float2 ga3 = *reinterpret_cast<const float2*>(&Gl[(4 * kb + 3) * 66 + 2 * l]);
#pragma unroll
    for (int i = 0; i < 8; ++i) {
      const float4 sv = *reinterpret_cast<const float4*>(&sst[(8 * tw + i) * 64 + 4 * kb]);
      acc0[i] = fmaf(ga3.x, sv.w, fmaf(ga2.x, sv.z, fmaf(ga1.x, sv.y, fmaf(ga0.x, sv.x, acc0[i]))));
      acc1[i] = fmaf(ga3.y, sv.w, fmaf(ga2.y, sv.z, fmaf(ga1.y, sv.y, fmaf(ga0.y, sv.x, acc1[i]))));
    }
  }
#pragma unroll
  for (int i = 0; i < 8; ++i) {
    const int n = 8 * tw + i;
    const float2 sj = *reinterpret_cast<const float2*>(&sst[n * 64 + 2 * l]);
    part2[n * 33 + l] = acc0[i] * sj.x + acc1[i] * sj.y;
    ps[n * 33 + l] = sj.x * sj.x + sj.y * sj.y;
  }
  __syncthreads();
  for (int p = 0; p < 16; ++p) {
    const int i = p * 256 + t;
    const int nl = i >> 6, k = i & 63;
    sho[(size_t)(nb + nl) * DCC + k] = f2bf(sst[nl * 64 + k]);
  }
  if (t < 64) {
    float s = 0.f, sp = 0.f;
#pragma unroll
    for (int u = 0; u < 32; ++u) { s += part2[t * 33 + u]; sp += ps[t * 33 + u]; }
    const float rv = resil[nb + t] + EPS_RES_F;
    const float inv = 1.0f / rv;
    aux4o[nb + t] = make_float4(s, 0.5f * rv * rv, sqrtf(sp), inv * inv);
  }
}

// --------- exact f32 keys for the 1/64 subsample (rows n = 64*j, j<2048)
__global__ __launch_bounds__(256) void sub_kernel(
    const float* __restrict__ stored, const float* __restrict__ qGT,
    const float* __restrict__ q2g, const float4* __restrict__ aux4,
    float* __restrict__ skeys) {
  __shared__ __align__(16) float qg[64 * 128];
  __shared__ __align__(16) float sst[64 * 64];
  __shared__ float s2sub[64];
  __shared__ float ir2sub[64];
  const int t = threadIdx.x;
  const int jb = blockIdx.x * 64;
  const int qbase = blockIdx.y * 128;
  for (int p = 0; p < 32; ++p) {
    const int i = p * 256 + t;
    const int k = i >> 7, qq = i & 127;
    qg[k * 128 + qq] = qGT[(size_t)k * NQ + qbase + qq];
  }
#pragma unroll
  for (int p = 0; p < 4; ++p) {
    const int idx = p * 256 + t;
    const int r = idx >> 4, f4 = idx & 15;
    reinterpret_cast<float4*>(sst)[r * 16 + f4] =
        reinterpret_cast<const float4*>(stored + (size_t)(64 * (jb + r)) * DCC)[f4];
  }
  if (t < 64) {
    const float4 v = aux4[64 * (jb + t)];
    s2sub[t] = v.x;
    ir2sub[t] = v.w;
  }
  __syncthreads();
  const int l = t & 31, tw = t >> 5;
  const int q0 = 4 * l;
  float q2r[4];
#pragma unroll
  for (int qq = 0; qq < 4; ++qq) q2r[qq] = q2g[qbase + q0 + qq];
  float acc[4][8];
#pragma unroll
  for (int qq = 0; qq < 4; ++qq)
#pragma unroll
    for (int i = 0; i < 8; ++i) acc[qq][i] = 0.f;
  for (int kb = 0; kb < 16; ++kb) {
    const float4 qa0 = *reinterpret_cast<const float4*>(&qg[(4 * kb + 0) * 128 + q0]);
    const float4 qa1 = *reinterpret_cast<const float4*>(&qg[(4 * kb + 1) * 128 + q0]);
    const float4 qa2 = *reinterpret_cast<const float4*>(&qg[(4 * kb + 2) * 128 + q0]);
    const float4 qa3 = *reinterpret_cast<const float4*>(&qg[(4 * kb + 3) * 128 + q0]);
#pragma unroll
    for (int i = 0; i < 8; ++i) {
      const float4 sv = *reinterpret_cast<const float4*>(&sst[(8 * tw + i) * 64 + 4 * kb]);
      acc[0][i] = fmaf(qa3.x, sv.w, fmaf(qa2.x, sv.z, fmaf(qa1.x, sv.y, fmaf(qa0.x, sv.x, acc[0][i]))));
      acc[1][i] = fmaf(qa3.y, sv.w, fmaf(qa2.y, sv.z, fmaf(qa1.y, sv.y, fmaf(qa0.y, sv.x, acc[1][i]))));
      acc[2][i] = fmaf(qa3.z, sv.w, fmaf(qa2.z, sv.z, fmaf(qa1.z, sv.y, fmaf(qa0.z, sv.x, acc[2][i]))));
      acc[3][i] = fmaf(qa3.w, sv.w, fmaf(qa2.w, sv.z, fmaf(qa1.w, sv.y, fmaf(qa0.w, sv.x, acc[3][i]))));
    }
  }
#pragma unroll
  for (int i = 0; i < 8; ++i) {
    const int jl = 8 * tw + i;
    const float s2v = s2sub[jl];
    const float ir2v = ir2sub[jl];
#pragma unroll
    for (int qq = 0; qq < 4; ++qq) {
      const float d2 = fmaf(-2.f, acc[qq][i], q2r[qq] + s2v);
      const float key = (fmaxf(d2, 0.f) + EPS_SQRT_F) * ir2v;
      skeys[(size_t)(qbase + q0 + qq) * 2048 + jb + jl] = key;
    }
  }
}

// ---- tau[q] = 16th smallest subsample key (exact), *1.0001 margin
__global__ __launch_bounds__(256) void tau_select(
    const float* __restrict__ skeys, float* __restrict__ tau) {
  __shared__ float lk[256 * 17];
  __shared__ float wkv[4][16];
  const int t = threadIdx.x;
  const int lane = t & 63, w = t >> 6;
  const int q = blockIdx.x;
  float k16[16];
#pragma unroll
  for (int s = 0; s < 16; ++s) k16[s] = 3.0e38f;
  for (int i = t; i < 2048; i += 256) {
    const float key = skeys[(size_t)q * 2048 + i];
    if (key < k16[15]) {
#pragma unroll
      for (int s = 15; s >= 1; --s) {
        const bool dprev = key < k16[s - 1];
        const float nk = dprev ? k16[s - 1] : key;
        if (key < k16[s]) k16[s] = nk;
      }
      if (key < k16[0]) k16[0] = key;
    }
  }
#pragma unroll
  for (int s = 0; s < 16; ++s) lk[t * 17 + s] = k16[s];
  __syncthreads();
  {
    int ptr = 0;
    for (int r = 0; r < K_TOP; ++r) {
      float v = lk[t * 17 + ptr];
      int who = lane;
#pragma unroll
      for (int off = 32; off; off >>= 1) {
        const float ov = __shfl_xor(v, off);
        const int ow = __shfl_xor(who, off);
        if (ov < v || (ov == v && ow < who)) { v = ov; who = ow; }
      }
      if (lane == 0) wkv[w][r] = v;
      if (lane == who) ptr++;
    }
  }
  __syncthreads();
  if (w == 0) {
    float v = wkv[lane >> 4][lane & 15];
    float t16 = 0.f;
    for (int r = 0; r < K_TOP; ++r) {
      float mv = v;
      int who = lane;
#pragma unroll
      for (int off = 32; off; off >>= 1) {
        const float ov = __shfl_xor(mv, off);
        const int ow = __shfl_xor(who, off);
        if (ov < mv || (ov == mv && ow < who)) { mv = ov; who = ow; }
      }
      t16 = mv;
      if (lane == who) v = 3.0e38f;
    }
    if (lane == 0) tau[q] = t16 * 1.0001f;
  }
}

// --------------- MFMA screening pass: bf16-hi cross-GEMM + bounded filter
// ROUND-9 structure + hoisted B fragments; __launch_bounds__(256,5):
// 5 waves/SIMD x 96 regs (64 VGPR + 32 acc, unified file) = 480 <= 512 — fits
// without spill (r13's (256,8) forced 64 total -> spill catastrophe).
// LDS 5 x 18.9KB = 94.6KB <= 160KB. +25% resident waves for latency hiding.
// stores u64: [63:48] bf16-UP upper key, [47:32] bf16-DOWN lower key, [31:0] n
__global__ __launch_bounds__(256, 5) void main_mfma(
    const unsigned short* __restrict__ sh, const unsigned short* __restrict__ qGh,
    const float* __restrict__ q2g, const float* __restrict__ qeg,
    const float* __restrict__ taug, const float4* __restrict__ aux4,
    int* __restrict__ ccnt, int* __restrict__ ovcnt,
    unsigned int* __restrict__ ovf, u64t* __restrict__ cand) {
  __shared__ __align__(16) char smA[16384];    // 128 n-rows x 128B, XOR-swizzled
  __shared__ __align__(16) float4 auxl[128];   // per-row {s2,h,sn,ir2}
  __shared__ int cnt64[64];
  const int t = threadIdx.x;
  const int lane = t & 63, w = t >> 6;
  const int l15 = lane & 15, hi4 = (lane >> 4) << 2;
  const int chunk = blockIdx.x;    // 0..127 ; linear%8 == chunk%8 -> XCD pinned
  const int qbase = blockIdx.y * 64;
  const int sx = ((lane & 7) << 4) ^ ((lane >> 3) << 4);
  const int g16 = (lane >> 4) << 4;
  const int swz = (lane & 7) << 4;

  if (t < 64) cnt64[t] = 0;
  float q2h_r[4], tau_r[4], qe_r[4];
#pragma unroll
  for (int qi = 0; qi < 4; ++qi) {
    const int q = qbase + qi * 16 + l15;
    q2h_r[qi] = 0.5f * q2g[q];
    tau_r[qi] = taug[q];
    qe_r[qi] = qeg[q];
  }
  // hoisted B fragments (loop-invariant): bfr[kh][qi]
  short8v bfr[2][4];
#pragma unroll
  for (int kh = 0; kh < 2; ++kh)
#pragma unroll
    for (int qi = 0; qi < 4; ++qi)
      bfr[kh][qi] = *reinterpret_cast<const short8v*>(
          (const char*)qGh + (((size_t)(qbase + qi * 16 + l15)) << 7) + (kh << 6) + g16);
  const f32x4 z4 = {0.f, 0.f, 0.f, 0.f};

  for (int nt = 0; nt < 8; ++nt) {
    const int nb = chunk * CHR + nt * 128;
    __syncthreads();  // previous tile fully consumed
#pragma unroll
    for (int ii = 0; ii < 4; ++ii) {
      const int row = w * 32 + ii * 8 + (lane >> 3);
      gl_lds16((const char*)sh + (size_t)(nb + row) * 128 + sx,
               smA + w * 4096 + ii * 1024);
    }
    if (t < 128) auxl[t] = aux4[nb + t];
    __syncthreads();  // drains vmcnt (global_load_lds) + lds writes

    f32x4 acc[2][4];
#pragma unroll
    for (int kh = 0; kh < 2; ++kh) {
      const int kx = ((kh << 6) | g16) ^ swz;
#pragma unroll
      for (int ni = 0; ni < 2; ++ni) {
        const short8v af = *reinterpret_cast<const short8v*>(
            smA + ((w * 32 + ni * 16 + l15) << 7) + kx);
#pragma unroll
        for (int qi = 0; qi < 4; ++qi)
          acc[ni][qi] = (kh == 0)
              ? __builtin_amdgcn_mfma_f32_16x16x32_bf16(af, bfr[0][qi], z4, 0, 0, 0)
              : __builtin_amdgcn_mfma_f32_16x16x32_bf16(af, bfr[1][qi], acc[ni][qi], 0, 0, 0);
      }
    }
    // epilogue: C/D map col(q)=lane&15, row(n)=(lane>>4)*4+reg
#pragma unroll
    for (int ni = 0; ni < 2; ++ni) {
#pragma unroll
      for (int r = 0; r < 4; ++r) {
        const int nl = w * 32 + ni * 16 + hi4 + r;
        const float4 av = auxl[nl];  // {s2, h, sn, ir2}
#pragma unroll
        for (int qi = 0; qi < 4; ++qi) {
          const float a = acc[ni][qi][r];
          const float t1 = fmaf(0.5f, av.x, q2h_r[qi]);
          const float thr = fmaf(-qe_r[qi], av.z, fmaf(-tau_r[qi], av.y, t1));
          if (a >= thr) {
            const int ql = qi * 16 + l15;
            const int n = nb + nl;
            const float d2 = 2.0f * (t1 - a);
            const float keyp = (fmaxf(d2, 0.0f) + EPS_SQRT_F) * av.w;
            const float ev = fmaf(2.0f * qe_r[qi] * av.z, av.w, 1e-5f * keyp) * 1.0002f;
            const unsigned hiw = (bf16_up_pos(keyp + ev) << 16) |
                                 bf16_down_pos(fmaxf(keyp - ev, 0.0f));
            const u64t ce = ((u64t)hiw << 32) | (unsigned)n;
            const int pos = atomicAdd(&cnt64[ql], 1);   // LDS atomic (fast)
            if (pos < SLOTS) {
              cand[((size_t)((qbase + ql) * NCH + chunk)) * SLOTS + pos] = ce;
            } else {
              const int gp = atomicAdd(ovcnt, 1);        // global, rare
              if (gp < OVCAP) ovf[gp] = ((unsigned)(qbase + ql) << 17) | (unsigned)n;
            }
          }
        }
      }
    }
  }
  __syncthreads();
  if (t < 64) {
    int c = cnt64[t];
    if (c > SLOTS) c = SLOTS;
    ccnt[(size_t)(qbase + t) * NCH + chunk] = c;
  }
}

// ------ final: histogram-rank bracket prune + exact refine, 1 block / query
__global__ __launch_bounds__(256) void final_kernel(
    const u64t* __restrict__ cand, const int* __restrict__ ccnt,
    const int* __restrict__ ovcnt, const unsigned int* __restrict__ ovf,
    const float* __restrict__ qGr, const float* __restrict__ q2g,
    const float* __restrict__ stored, const float4* __restrict__ aux4,
    float* __restrict__ out) {
  __shared__ __align__(16) float qgl[64];
  __shared__ int ccl[NCH];
  __shared__ int hist[256];
  __shared__ int scnt;
  __shared__ unsigned int sidx[SCAP];
  __shared__ u64t wku[4][16];
  const int t = threadIdx.x;
  const int lane = t & 63, w = t >> 6;
  const int q = blockIdx.x;
  if (t < 64) qgl[t] = qGr[(size_t)q * DCC + t];
  if (t < NCH) ccl[t] = min(ccnt[(size_t)q * NCH + t], SLOTS);
  hist[t] = 0;
  if (t == 0) scnt = 0;
  __syncthreads();
  u64t ev[EPT];
  unsigned vmask = 0;
  {
    const u64t* base = cand + (size_t)q * NCH * SLOTS;
#pragma unroll
    for (int p = 0; p < EPT; ++p) {
      const int i = p * 256 + t;
      ev[p] = base[i];
      const int seg = i / SLOTS;
      const int j = i - seg * SLOTS;
      if (j < ccl[seg]) vmask |= 1u << p;
    }
  }
#pragma unroll
  for (int p = 0; p < EPT; ++p)
    if (vmask & (1u << p)) atomicAdd(&hist[(int)(ev[p] >> 56)], 1);
  __syncthreads();
  int B, baseB, total;
  bin_rank256(hist, K_TOP - 1, lane, B, baseB, total);
  unsigned U16bits = 0xFFFFu;
  __syncthreads();
  if (total >= K_TOP) {
    hist[t] = 0;
    __syncthreads();
#pragma unroll
    for (int p = 0; p < EPT; ++p)
      if ((vmask & (1u << p)) && (int)(ev[p] >> 56) == B)
        atomicAdd(&hist[(int)((ev[p] >> 48) & 0xFF)], 1);
    __syncthreads();
    int b2, dummy, tot2;
    bin_rank256(hist, K_TOP - 1 - baseB, lane, b2, dummy, tot2);
    U16bits = ((unsigned)B << 8) | (unsigned)b2;
  }
#pragma unroll
  for (int p = 0; p < EPT; ++p) {
    if ((vmask & (1u << p)) && ((unsigned)(ev[p] >> 32) & 0xFFFFu) <= U16bits) {
      const int pos = atomicAdd(&scnt, 1);
      if (pos < SCAP) sidx[pos] = (unsigned)ev[p];
    }
  }
  {
    int oc = *ovcnt;
    if (oc > OVCAP) oc = OVCAP;
    for (int i = t; i < oc; i += 256) {
      const unsigned pk = ovf[i];
      if ((int)(pk >> 17) == q) {
        const int pos = atomicAdd(&scnt, 1);
        if (pos < SCAP) sidx[pos] = pk & 0x1FFFFu;
      }
    }
  }
  __syncthreads();
  int sc = scnt;
  if (sc > SCAP) sc = SCAP;
  const float q2v = q2g[q];
  u64t k16u[16];
#pragma unroll
  for (int s = 0; s < 16; ++s) k16u[s] = ~0ULL;
  for (int i = t; i < sc; i += 256) {
    const int n = (int)sidx[i];
    const u64t pv =
        ((u64t)__float_as_uint(exact_key(stored, qgl, q2v, aux4, n)) << 32) | (unsigned)n;
    if (pv < k16u[15]) {
#pragma unroll
      for (int s = 15; s >= 1; --s) {
        const bool dprev = pv < k16u[s - 1];
        const u64t nk = dprev ? k16u[s - 1] : pv;
        if (pv < k16u[s]) k16u[s] = nk;
      }
      if (pv < k16u[0]) k16u[0] = pv;
    }
  }
  {
    int ptr = 0;
    for (int r = 0; r < K_TOP; ++r) {
      u64t v = k16u[ptr];
      int who = lane;
#pragma unroll
      for (int off = 32; off; off >>= 1) {
        const u64t ov = __shfl_xor(v, off);
        const int ol = __shfl_xor(who, off);
        if (ov < v || (ov == v && ol < who)) { v = ov; who = ol; }
      }
      if (lane == 0) wku[w][r] = v;
      if (lane == who) ptr++;
    }
  }
  __syncthreads();
  if (w == 0) {
    u64t e = wku[lane >> 4][lane & 15];
    for (int r = 0; r < K_TOP; ++r) {
      u64t mv = e;
      int who = lane;
#pragma unroll
      for (int off = 32; off; off >>= 1) {
        const u64t ov = __shfl_xor(mv, off);
        const int ol = __shfl_xor(who, off);
        if (ov < mv || (ov == mv && ol < who)) { mv = ov; who = ol; }
      }
      if (lane == 0) {
        out[q * K_TOP + r] = sqrtf(__uint_as_float((unsigned)(mv >> 32)));
        out[NQ * K_TOP + q * K_TOP + r] = (float)(unsigned)(mv & 0xFFFFFFFFu);
      }
      if (lane == who) e = ~0ULL;
    }
  }
}

// ----------------------------------------------------------------- launcher
extern "C" void kernel_launch(void* const* d_in, const int* in_sizes, int n_in,
                              void* d_out, int out_size, void* d_ws, size_t ws_size,
                              hipStream_t stream) {
  const float* query  = (const float*)d_in[0];
  const float* stored = (const float*)d_in[1];
  const float* resil  = (const float*)d_in[2];
  const float* W      = (const float*)d_in[3];
  const float* M      = (const float*)d_in[4];

  char* ws = (char*)d_ws;
  size_t off = 0;
  float* G    = (float*)(ws + off); off += 16384;
  float* qGT  = (float*)(ws + off); off += 262144;   // [64][1024] f32
  float* qGr  = (float*)(ws + off); off += 262144;   // [1024][64] f32
  unsigned short* qGh = (unsigned short*)(ws + off); off += 131072;  // bf16
  float* q2   = (float*)(ws + off); off += 4096;
  float* qe   = (float*)(ws + off); off += 4096;
  float* tau  = (float*)(ws + off); off += 4096;
  float4* aux4 = (float4*)(ws + off); off += (size_t)NS * 16;  // 2 MB
  int*   ccnt = (int*)(ws + off);   off += (size_t)NQ * NCH * 4;  // 512 KB
  int*   ovcnt = (int*)(ws + off);  off += 4096;
  unsigned int* ovf = (unsigned int*)(ws + off); off += OVCAP * 4;  // 256 KB
  unsigned short* sh = (unsigned short*)(ws + off); off += 16777216;  // bf16 rows
  u64t* cand = (u64t*)(ws + off);   // [NQ][NCH][SLOTS] u64 = 24 MB
  float* skeys = (float*)cand;      // overlay (first 8 MB, used before cand)

  float* out = (float*)d_out;

  hipMemsetAsync(ovcnt, 0, 4096, stream);
  g_kernel<<<16, 256, 0, stream>>>(M, G);
  q_kernel<<<NQ / 4, 256, 0, stream>>>(query, W, G, qGT, qGr, qGh, q2, qe);
  s_kernel<<<NS / 64, 256, 0, stream>>>(stored, resil, G, aux4, sh);
  sub_kernel<<<dim3(32, 8), 256, 0, stream>>>(stored, qGT, q2, aux4, skeys);
  tau_select<<<NQ, 256, 0, stream>>>(skeys, tau);
  main_mfma<<<dim3(NCH, NQ / 64), 256, 0, stream>>>(sh, qGh, q2, qe, tau, aux4,
                                                    ccnt, ovcnt, ovf, cand);
  final_kernel<<<NQ, 256, 0, stream>>>(cand, ccnt, ovcnt, ovf, qGr, q2,
                                       stored, aux4, out);
}

// Round 16
// 196.447 us; speedup vs baseline: 1.2078x; 1.2078x over previous
//
#include <hip/hip_runtime.h>
#include <stdint.h>

// Problem constants (fixed by the reference)
#define NQ 1024
#define NS 131072
#define DMM 2048
#define DCC 64
#define K_TOP 16
#define EPS_RES_F 1e-8f
#define EPS_SQRT_F 1e-12f
#define EPS_A 0.01f       // bf16 hi-only dot abs-error coeff (rigorous bound ~0.004)

#define NCH 128           // candidate chunks over N
#define CHR (NS / NCH)    // 1024 rows per chunk
#define OVCAP 65536       // global overflow list capacity (rare)
#define SLOTS 24          // per-(q,chunk) candidate slots
#define MTOT (NCH * SLOTS)        // 3072 entries per query
#define EPT (MTOT / 256)          // 12 entries per thread
#define SCAP 3328         // survivor capacity >= MTOT + ovf slack

typedef __attribute__((ext_vector_type(8))) short short8v;  // 8 x bf16
typedef __attribute__((ext_vector_type(4))) float f32x4;
typedef unsigned long long u64t;

__device__ __forceinline__ unsigned short f2bf(float x) {  // RNE f32->bf16
  unsigned u = __float_as_uint(x);
  unsigned r = (u + 0x7FFFu + ((u >> 16) & 1u)) >> 16;
  return (unsigned short)r;
}
// directed bf16 rounding for POSITIVE floats (bounds stay provable)
__device__ __forceinline__ unsigned bf16_down_pos(float x) {
  return __float_as_uint(x) >> 16;
}
__device__ __forceinline__ unsigned bf16_up_pos(float x) {
  const unsigned u = __float_as_uint(x);
  return (u >> 16) + ((u & 0xFFFFu) ? 1u : 0u);
}

__device__ __forceinline__ void gl_lds16(const void* g, void* l) {
  __builtin_amdgcn_global_load_lds(
      (const __attribute__((address_space(1))) unsigned int*)g,
      (__attribute__((address_space(3))) unsigned int*)l, 16, 0, 0);
}

// exact key chain — MUST stay bit-identical to sub_kernel's accumulation
__device__ __forceinline__ float exact_key(const float* __restrict__ stored,
                                           const float* qgl, float q2v,
                                           const float4* __restrict__ aux4, int n) {
  const float4* srow = reinterpret_cast<const float4*>(stored + (size_t)n * DCC);
  float a = 0.f;
#pragma unroll
  for (int kb = 0; kb < 16; ++kb) {
    const float4 qv = *reinterpret_cast<const float4*>(&qgl[4 * kb]);
    const float4 sv = srow[kb];
    a = fmaf(qv.w, sv.w, fmaf(qv.z, sv.z, fmaf(qv.y, sv.y, fmaf(qv.x, sv.x, a))));
  }
  const float4 av = aux4[n];
  const float d2 = fmaf(-2.f, a, q2v + av.x);
  return (fmaxf(d2, 0.f) + EPS_SQRT_F) * av.w;
}

// All lanes of a wave: find the bin containing 0-based `rank` in hist[256]
__device__ __forceinline__ void bin_rank256(const int* hist, int rank, int lane,
                                            int& binOut, int& baseOut, int& totalOut) {
  const int b0 = hist[4 * lane + 0], b1 = hist[4 * lane + 1];
  const int b2 = hist[4 * lane + 2], b3 = hist[4 * lane + 3];
  const int s01 = b0 + b1, s012 = s01 + b2;
  const int s = s012 + b3;
  int inc = s;
#pragma unroll
  for (int off = 1; off < 64; off <<= 1) {
    const int u = __shfl_up(inc, off);
    if (lane >= off) inc += u;
  }
  totalOut = __shfl(inc, 63);
  const int excl = inc - s;
  const bool has = (excl <= rank) && (rank < inc);
  const unsigned long long mask = __ballot(has);
  if (mask == 0ULL) { binOut = -1; baseOut = 0; return; }
  const int who = __ffsll((unsigned long long)mask) - 1;
  const int exclW = __shfl(excl, who);
  const int c0 = __shfl(b0, who);
  const int c01 = __shfl(s01, who);
  const int c012 = __shfl(s012, who);
  const int r = rank - exclW;
  int sub, base;
  if (r < c0) { sub = 0; base = 0; }
  else if (r < c01) { sub = 1; base = c0; }
  else if (r < c012) { sub = 2; base = c01; }
  else { sub = 3; base = c012; }
  binOut = 4 * who + sub;
  baseOut = exclW + base;
}

// ---------------------------------------------------------------- G = M M^T
__global__ __launch_bounds__(256) void g_kernel(const float* __restrict__ M,
                                                float* __restrict__ G) {
  __shared__ __align__(16) float Ml[64 * 66];
  const int t = threadIdx.x;
  for (int p = 0; p < 16; ++p) {
    int i = p * 256 + t;
    Ml[(i >> 6) * 66 + (i & 63)] = M[i];
  }
  __syncthreads();
  const int e = blockIdx.x * 256 + t;
  const int i = e >> 6, j = e & 63;
  float a = 0.f;
#pragma unroll
  for (int k = 0; k < 64; ++k) a = fmaf(Ml[i * 66 + k], Ml[j * 66 + k], a);
  G[e] = a;
}

// ---------------- qc = q W ; qG = qc G ; q2 = qc.qG ; qGh bf16 ; qe = eps*|qG|
// ROUND-9 KNOWN-GOOD VERSION, byte-for-byte. qc summation order is
// ordering-critical (r11 failure); r10/r14 restructurings were slower. FROZEN.
__global__ __launch_bounds__(256) void q_kernel(
    const float* __restrict__ query, const float* __restrict__ W,
    const float* __restrict__ G, float* __restrict__ qGT,
    float* __restrict__ qGr, unsigned short* __restrict__ qGh,
    float* __restrict__ q2o, float* __restrict__ qeo) {
  __shared__ __align__(16) float qs[4][DMM];
  __shared__ float part[4][4][64];
  __shared__ float qc[4][64];
  const int t = threadIdx.x;
  const int qb = blockIdx.x * 4;
  {
    const float4* src = reinterpret_cast<const float4*>(query + (size_t)qb * DMM);
    float4* dst = reinterpret_cast<float4*>(&qs[0][0]);
#pragma unroll
    for (int r = 0; r < 8; ++r) dst[r * 256 + t] = src[r * 256 + t];
  }
  __syncthreads();
  const int c = t & 63, seg = t >> 6;
  float p0 = 0.f, p1 = 0.f, p2 = 0.f, p3 = 0.f;
  const int kbase = seg * 512;
  for (int ki = 0; ki < 512; ++ki) {
    const int k = kbase + ki;
    const float w = W[(size_t)k * 64 + c];
    p0 = fmaf(qs[0][k], w, p0);
    p1 = fmaf(qs[1][k], w, p1);
    p2 = fmaf(qs[2][k], w, p2);
    p3 = fmaf(qs[3][k], w, p3);
  }
  part[0][seg][c] = p0; part[1][seg][c] = p1;
  part[2][seg][c] = p2; part[3][seg][c] = p3;
  __syncthreads();
  {
    const int q = t >> 6, cc = t & 63;
    qc[q][cc] = part[q][0][cc] + part[q][1][cc] + part[q][2][cc] + part[q][3][cc];
  }
  __syncthreads();
  const int w = t >> 6, lane = t & 63;
  float g = 0.f;
  for (int j = 0; j < 64; ++j) g = fmaf(qc[w][j], G[j * 64 + lane], g);
  const int q = qb + w;
  qGT[(size_t)lane * NQ + q] = g;
  qGr[(size_t)q * DCC + lane] = g;
  qGh[(size_t)q * DCC + lane] = f2bf(g);
  float pr = qc[w][lane] * g;
  float pn = g * g;
#pragma unroll
  for (int off = 32; off; off >>= 1) {
    pr += __shfl_xor(pr, off);
    pn += __shfl_xor(pn, off);
  }
  if (lane == 0) {
    q2o[q] = pr;
    qeo[q] = EPS_A * sqrtf(pn);
  }
}

// ---- aux4[n] = { s2, h=(res+eps)^2/2, sn=|s|, ir2 } ; sh = bf16(stored rows)
// ROUND-9 KNOWN-GOOD VERSION, byte-for-byte. FROZEN.
__global__ __launch_bounds__(256) void s_kernel(
    const float* __restrict__ stored, const float* __restrict__ resil,
    const float* __restrict__ G, float4* __restrict__ aux4o,
    unsigned short* __restrict__ sho) {
  __shared__ __align__(16) float Gl[64 * 66];
  __shared__ __align__(16) float sst[64 * 64];
  __shared__ float part2[64 * 33];
  __shared__ float ps[64 * 33];
  const int t = threadIdx.x;
  const int nb = blockIdx.x * 64;
  for (int p = 0; p < 16; ++p) {
    int i = p * 256 + t;
    Gl[(i >> 6) * 66 + (i & 63)] = G[i];
  }
  {
    const float4* src = reinterpret_cast<const float4*>(stored + (size_t)nb * DCC);
    float4* dst = reinterpret_cast<float4*>(sst);
#pragma unroll
    for (int r = 0; r < 4; ++r) dst[r * 256 + t] = src[r * 256 + t];
  }
  __syncthreads();
  const int l = t & 31, tw = t >> 5;
  float acc0[8], acc1[8];
#pragma unroll
  for (int i = 0; i < 8; ++i) { acc0[i] = 0.f; acc1[i] = 0.f; }
  for (int kb = 0; kb < 16; ++kb) {
    const float2 ga0 = *reinterpret_cast<const float2*>(&Gl[(4 * kb + 0) * 66 + 2 * l]);
    const float2 ga1 = *reinterpret_cast<const float2*>(&Gl[(4 * kb + 1) * 66 + 2 * l]);
    const float2 ga2 = *reinterpret_cast<const float2*>(&Gl[(4 * kb + 2) * 66 + 2 * l]);
    const float2 ga3 = *reinterpret_cast<const float2*>(&Gl[(4 * kb + 3) * 66 + 2 * l]);
#pragma unroll
    for (int i = 0; i < 8; ++i) {
      const float4 sv = *reinterpret_cast<const float4*>(&sst[(8 * tw + i) * 64 + 4 * kb]);
      acc0[i] = fmaf(ga3.x, sv.w, fmaf(ga2.x, sv.z, fmaf(ga1.x, sv.y, fmaf(ga0.x, sv.x, acc0[i]))));
      acc1[i] = fmaf(ga3.y, sv.w, fmaf(ga2.y, sv.z, fmaf(ga1.y, sv.y, fmaf(ga0.y, sv.x, acc1[i]))));
    }
  }
#pragma unroll
  for (int i = 0; i < 8; ++i) {
    const int n = 8 * tw + i;
    const float2 sj = *reinterpret_cast<const float2*>(&sst[n * 64 + 2 * l]);
    part2[n * 33 + l] = acc0[i] * sj.x + acc1[i] * sj.y;
    ps[n * 33 + l] = sj.x * sj.x + sj.y * sj.y;
  }
  __syncthreads();
  for (int p = 0; p < 16; ++p) {
    const int i = p * 256 + t;
    const int nl = i >> 6, k = i & 63;
    sho[(size_t)(nb + nl) * DCC + k] = f2bf(sst[nl * 64 + k]);
  }
  if (t < 64) {
    float s = 0.f, sp = 0.f;
#pragma unroll
    for (int u = 0; u < 32; ++u) { s += part2[t * 33 + u]; sp += ps[t * 33 + u]; }
    const float rv = resil[nb + t] + EPS_RES_F;
    const float inv = 1.0f / rv;
    aux4o[nb + t] = make_float4(s, 0.5f * rv * rv, sqrtf(sp), inv * inv);
  }
}

// --------- exact f32 keys for the 1/64 subsample (rows n = 64*j, j<2048)
__global__ __launch_bounds__(256) void sub_kernel(
    const float* __restrict__ stored, const float* __restrict__ qGT,
    const float* __restrict__ q2g, const float4* __restrict__ aux4,
    float* __restrict__ skeys) {
  __shared__ __align__(16) float qg[64 * 128];
  __shared__ __align__(16) float sst[64 * 64];
  __shared__ float s2sub[64];
  __shared__ float ir2sub[64];
  const int t = threadIdx.x;
  const int jb = blockIdx.x * 64;
  const int qbase = blockIdx.y * 128;
  for (int p = 0; p < 32; ++p) {
    const int i = p * 256 + t;
    const int k = i >> 7, qq = i & 127;
    qg[k * 128 + qq] = qGT[(size_t)k * NQ + qbase + qq];
  }
#pragma unroll
  for (int p = 0; p < 4; ++p) {
    const int idx = p * 256 + t;
    const int r = idx >> 4, f4 = idx & 15;
    reinterpret_cast<float4*>(sst)[r * 16 + f4] =
        reinterpret_cast<const float4*>(stored + (size_t)(64 * (jb + r)) * DCC)[f4];
  }
  if (t < 64) {
    const float4 v = aux4[64 * (jb + t)];
    s2sub[t] = v.x;
    ir2sub[t] = v.w;
  }
  __syncthreads();
  const int l = t & 31, tw = t >> 5;
  const int q0 = 4 * l;
  float q2r[4];
#pragma unroll
  for (int qq = 0; qq < 4; ++qq) q2r[qq] = q2g[qbase + q0 + qq];
  float acc[4][8];
#pragma unroll
  for (int qq = 0; qq < 4; ++qq)
#pragma unroll
    for (int i = 0; i < 8; ++i) acc[qq][i] = 0.f;
  for (int kb = 0; kb < 16; ++kb) {
    const float4 qa0 = *reinterpret_cast<const float4*>(&qg[(4 * kb + 0) * 128 + q0]);
    const float4 qa1 = *reinterpret_cast<const float4*>(&qg[(4 * kb + 1) * 128 + q0]);
    const float4 qa2 = *reinterpret_cast<const float4*>(&qg[(4 * kb + 2) * 128 + q0]);
    const float4 qa3 = *reinterpret_cast<const float4*>(&qg[(4 * kb + 3) * 128 + q0]);
#pragma unroll
    for (int i = 0; i < 8; ++i) {
      const float4 sv = *reinterpret_cast<const float4*>(&sst[(8 * tw + i) * 64 + 4 * kb]);
      acc[0][i] = fmaf(qa3.x, sv.w, fmaf(qa2.x, sv.z, fmaf(qa1.x, sv.y, fmaf(qa0.x, sv.x, acc[0][i]))));
      acc[1][i] = fmaf(qa3.y, sv.w, fmaf(qa2.y, sv.z, fmaf(qa1.y, sv.y, fmaf(qa0.y, sv.x, acc[1][i]))));
      acc[2][i] = fmaf(qa3.z, sv.w, fmaf(qa2.z, sv.z, fmaf(qa1.z, sv.y, fmaf(qa0.z, sv.x, acc[2][i]))));
      acc[3][i] = fmaf(qa3.w, sv.w, fmaf(qa2.w, sv.z, fmaf(qa1.w, sv.y, fmaf(qa0.w, sv.x, acc[3][i]))));
    }
  }
#pragma unroll
  for (int i = 0; i < 8; ++i) {
    const int jl = 8 * tw + i;
    const float s2v = s2sub[jl];
    const float ir2v = ir2sub[jl];
#pragma unroll
    for (int qq = 0; qq < 4; ++qq) {
      const float d2 = fmaf(-2.f, acc[qq][i], q2r[qq] + s2v);
      const float key = (fmaxf(d2, 0.f) + EPS_SQRT_F) * ir2v;
      skeys[(size_t)(qbase + q0 + qq) * 2048 + jb + jl] = key;
    }
  }
}

// ---- tau[q] = 16th smallest subsample key (exact), *1.0001 margin
__global__ __launch_bounds__(256) void tau_select(
    const float* __restrict__ skeys, float* __restrict__ tau) {
  __shared__ float lk[256 * 17];
  __shared__ float wkv[4][16];
  const int t = threadIdx.x;
  const int lane = t & 63, w = t >> 6;
  const int q = blockIdx.x;
  float k16[16];
#pragma unroll
  for (int s = 0; s < 16; ++s) k16[s] = 3.0e38f;
  for (int i = t; i < 2048; i += 256) {
    const float key = skeys[(size_t)q * 2048 + i];
    if (key < k16[15]) {
#pragma unroll
      for (int s = 15; s >= 1; --s) {
        const bool dprev = key < k16[s - 1];
        const float nk = dprev ? k16[s - 1] : key;
        if (key < k16[s]) k16[s] = nk;
      }
      if (key < k16[0]) k16[0] = key;
    }
  }
#pragma unroll
  for (int s = 0; s < 16; ++s) lk[t * 17 + s] = k16[s];
  __syncthreads();
  {
    int ptr = 0;
    for (int r = 0; r < K_TOP; ++r) {
      float v = lk[t * 17 + ptr];
      int who = lane;
#pragma unroll
      for (int off = 32; off; off >>= 1) {
        const float ov = __shfl_xor(v, off);
        const int ow = __shfl_xor(who, off);
        if (ov < v || (ov == v && ow < who)) { v = ov; who = ow; }
      }
      if (lane == 0) wkv[w][r] = v;
      if (lane == who) ptr++;
    }
  }
  __syncthreads();
  if (w == 0) {
    float v = wkv[lane >> 4][lane & 15];
    float t16 = 0.f;
    for (int r = 0; r < K_TOP; ++r) {
      float mv = v;
      int who = lane;
#pragma unroll
      for (int off = 32; off; off >>= 1) {
        const float ov = __shfl_xor(mv, off);
        const int ow = __shfl_xor(who, off);
        if (ov < mv || (ov == mv && ow < who)) { mv = ov; who = ow; }
      }
      t16 = mv;
      if (lane == who) v = 3.0e38f;
    }
    if (lane == 0) tau[q] = t16 * 1.0001f;
  }
}

// --------------- MFMA screening pass: bf16-hi cross-GEMM + bounded filter
// PROVEN OPTIMUM CONFIG (r9/r14: 72.5us): LDS-staged A tile, (256,4),
// hoisted loop-invariant B fragments. Occupancy ledger: (256,5) and (256,8)
// both SPILL (unified VGPR+AGPR file, ~96+ regs/wave needed; r13/r15);
// direct-load = 86us (r12); dbuf = 73.4us (r10). Do not touch.
// stores u64: [63:48] bf16-UP upper key, [47:32] bf16-DOWN lower key, [31:0] n
__global__ __launch_bounds__(256, 4) void main_mfma(
    const unsigned short* __restrict__ sh, const unsigned short* __restrict__ qGh,
    const float* __restrict__ q2g, const float* __restrict__ qeg,
    const float* __restrict__ taug, const float4* __restrict__ aux4,
    int* __restrict__ ccnt, int* __restrict__ ovcnt,
    unsigned int* __restrict__ ovf, u64t* __restrict__ cand) {
  __shared__ __align__(16) char smA[16384];    // 128 n-rows x 128B, XOR-swizzled
  __shared__ __align__(16) float4 auxl[128];   // per-row {s2,h,sn,ir2}
  __shared__ int cnt64[64];
  const int t = threadIdx.x;
  const int lane = t & 63, w = t >> 6;
  const int l15 = lane & 15, hi4 = (lane >> 4) << 2;
  const int chunk = blockIdx.x;    // 0..127 ; linear%8 == chunk%8 -> XCD pinned
  const int qbase = blockIdx.y * 64;
  const int sx = ((lane & 7) << 4) ^ ((lane >> 3) << 4);
  const int g16 = (lane >> 4) << 4;
  const int swz = (lane & 7) << 4;

  if (t < 64) cnt64[t] = 0;
  float q2h_r[4], tau_r[4], qe_r[4];
#pragma unroll
  for (int qi = 0; qi < 4; ++qi) {
    const int q = qbase + qi * 16 + l15;
    q2h_r[qi] = 0.5f * q2g[q];
    tau_r[qi] = taug[q];
    qe_r[qi] = qeg[q];
  }
  // hoisted B fragments (loop-invariant): bfr[kh][qi]
  short8v bfr[2][4];
#pragma unroll
  for (int kh = 0; kh < 2; ++kh)
#pragma unroll
    for (int qi = 0; qi < 4; ++qi)
      bfr[kh][qi] = *reinterpret_cast<const short8v*>(
          (const char*)qGh + (((size_t)(qbase + qi * 16 + l15)) << 7) + (kh << 6) + g16);
  const f32x4 z4 = {0.f, 0.f, 0.f, 0.f};

  for (int nt = 0; nt < 8; ++nt) {
    const int nb = chunk * CHR + nt * 128;
    __syncthreads();  // previous tile fully consumed
#pragma unroll
    for (int ii = 0; ii < 4; ++ii) {
      const int row = w * 32 + ii * 8 + (lane >> 3);
      gl_lds16((const char*)sh + (size_t)(nb + row) * 128 + sx,
               smA + w * 4096 + ii * 1024);
    }
    if (t < 128) auxl[t] = aux4[nb + t];
    __syncthreads();  // drains vmcnt (global_load_lds) + lds writes

    f32x4 acc[2][4];
#pragma unroll
    for (int kh = 0; kh < 2; ++kh) {
      const int kx = ((kh << 6) | g16) ^ swz;
#pragma unroll
      for (int ni = 0; ni < 2; ++ni) {
        const short8v af = *reinterpret_cast<const short8v*>(
            smA + ((w * 32 + ni * 16 + l15) << 7) + kx);
#pragma unroll
        for (int qi = 0; qi < 4; ++qi)
          acc[ni][qi] = (kh == 0)
              ? __builtin_amdgcn_mfma_f32_16x16x32_bf16(af, bfr[0][qi], z4, 0, 0, 0)
              : __builtin_amdgcn_mfma_f32_16x16x32_bf16(af, bfr[1][qi], acc[ni][qi], 0, 0, 0);
      }
    }
    // epilogue: C/D map col(q)=lane&15, row(n)=(lane>>4)*4+reg
#pragma unroll
    for (int ni = 0; ni < 2; ++ni) {
#pragma unroll
      for (int r = 0; r < 4; ++r) {
        const int nl = w * 32 + ni * 16 + hi4 + r;
        const float4 av = auxl[nl];  // {s2, h, sn, ir2}
#pragma unroll
        for (int qi = 0; qi < 4; ++qi) {
          const float a = acc[ni][qi][r];
          const float t1 = fmaf(0.5f, av.x, q2h_r[qi]);
          const float thr = fmaf(-qe_r[qi], av.z, fmaf(-tau_r[qi], av.y, t1));
          if (a >= thr) {
            const int ql = qi * 16 + l15;
            const int n = nb + nl;
            const float d2 = 2.0f * (t1 - a);
            const float keyp = (fmaxf(d2, 0.0f) + EPS_SQRT_F) * av.w;
            const float ev = fmaf(2.0f * qe_r[qi] * av.z, av.w, 1e-5f * keyp) * 1.0002f;
            const unsigned hiw = (bf16_up_pos(keyp + ev) << 16) |
                                 bf16_down_pos(fmaxf(keyp - ev, 0.0f));
            const u64t ce = ((u64t)hiw << 32) | (unsigned)n;
            const int pos = atomicAdd(&cnt64[ql], 1);   // LDS atomic (fast)
            if (pos < SLOTS) {
              cand[((size_t)((qbase + ql) * NCH + chunk)) * SLOTS + pos] = ce;
            } else {
              const int gp = atomicAdd(ovcnt, 1);        // global, rare
              if (gp < OVCAP) ovf[gp] = ((unsigned)(qbase + ql) << 17) | (unsigned)n;
            }
          }
        }
      }
    }
  }
  __syncthreads();
  if (t < 64) {
    int c = cnt64[t];
    if (c > SLOTS) c = SLOTS;
    ccnt[(size_t)(qbase + t) * NCH + chunk] = c;
  }
}

// ------ final: histogram-rank bracket prune + exact refine, 1 block / query
__global__ __launch_bounds__(256) void final_kernel(
    const u64t* __restrict__ cand, const int* __restrict__ ccnt,
    const int* __restrict__ ovcnt, const unsigned int* __restrict__ ovf,
    const float* __restrict__ qGr, const float* __restrict__ q2g,
    const float* __restrict__ stored, const float4* __restrict__ aux4,
    float* __restrict__ out) {
  __shared__ __align__(16) float qgl[64];
  __shared__ int ccl[NCH];
  __shared__ int hist[256];
  __shared__ int scnt;
  __shared__ unsigned int sidx[SCAP];
  __shared__ u64t wku[4][16];
  const int t = threadIdx.x;
  const int lane = t & 63, w = t >> 6;
  const int q = blockIdx.x;
  if (t < 64) qgl[t] = qGr[(size_t)q * DCC + t];
  if (t < NCH) ccl[t] = min(ccnt[(size_t)q * NCH + t], SLOTS);
  hist[t] = 0;
  if (t == 0) scnt = 0;
  __syncthreads();
  u64t ev[EPT];
  unsigned vmask = 0;
  {
    const u64t* base = cand + (size_t)q * NCH * SLOTS;
#pragma unroll
    for (int p = 0; p < EPT; ++p) {
      const int i = p * 256 + t;
      ev[p] = base[i];
      const int seg = i / SLOTS;
      const int j = i - seg * SLOTS;
      if (j < ccl[seg]) vmask |= 1u << p;
    }
  }
#pragma unroll
  for (int p = 0; p < EPT; ++p)
    if (vmask & (1u << p)) atomicAdd(&hist[(int)(ev[p] >> 56)], 1);
  __syncthreads();
  int B, baseB, total;
  bin_rank256(hist, K_TOP - 1, lane, B, baseB, total);
  unsigned U16bits = 0xFFFFu;
  __syncthreads();
  if (total >= K_TOP) {
    hist[t] = 0;
    __syncthreads();
#pragma unroll
    for (int p = 0; p < EPT; ++p)
      if ((vmask & (1u << p)) && (int)(ev[p] >> 56) == B)
        atomicAdd(&hist[(int)((ev[p] >> 48) & 0xFF)], 1);
    __syncthreads();
    int b2, dummy, tot2;
    bin_rank256(hist, K_TOP - 1 - baseB, lane, b2, dummy, tot2);
    U16bits = ((unsigned)B << 8) | (unsigned)b2;
  }
#pragma unroll
  for (int p = 0; p < EPT; ++p) {
    if ((vmask & (1u << p)) && ((unsigned)(ev[p] >> 32) & 0xFFFFu) <= U16bits) {
      const int pos = atomicAdd(&scnt, 1);
      if (pos < SCAP) sidx[pos] = (unsigned)ev[p];
    }
  }
  {
    int oc = *ovcnt;
    if (oc > OVCAP) oc = OVCAP;
    for (int i = t; i < oc; i += 256) {
      const unsigned pk = ovf[i];
      if ((int)(pk >> 17) == q) {
        const int pos = atomicAdd(&scnt, 1);
        if (pos < SCAP) sidx[pos] = pk & 0x1FFFFu;
      }
    }
  }
  __syncthreads();
  int sc = scnt;
  if (sc > SCAP) sc = SCAP;
  const float q2v = q2g[q];
  u64t k16u[16];
#pragma unroll
  for (int s = 0; s < 16; ++s) k16u[s] = ~0ULL;
  for (int i = t; i < sc; i += 256) {
    const int n = (int)sidx[i];
    const u64t pv =
        ((u64t)__float_as_uint(exact_key(stored, qgl, q2v, aux4, n)) << 32) | (unsigned)n;
    if (pv < k16u[15]) {
#pragma unroll
      for (int s = 15; s >= 1; --s) {
        const bool dprev = pv < k16u[s - 1];
        const u64t nk = dprev ? k16u[s - 1] : pv;
        if (pv < k16u[s]) k16u[s] = nk;
      }
      if (pv < k16u[0]) k16u[0] = pv;
    }
  }
  {
    int ptr = 0;
    for (int r = 0; r < K_TOP; ++r) {
      u64t v = k16u[ptr];
      int who = lane;
#pragma unroll
      for (int off = 32; off; off >>= 1) {
        const u64t ov = __shfl_xor(v, off);
        const int ol = __shfl_xor(who, off);
        if (ov < v || (ov == v && ol < who)) { v = ov; who = ol; }
      }
      if (lane == 0) wku[w][r] = v;
      if (lane == who) ptr++;
    }
  }
  __syncthreads();
  if (w == 0) {
    u64t e = wku[lane >> 4][lane & 15];
    for (int r = 0; r < K_TOP; ++r) {
      u64t mv = e;
      int who = lane;
#pragma unroll
      for (int off = 32; off; off >>= 1) {
        const u64t ov = __shfl_xor(mv, off);
        const int ol = __shfl_xor(who, off);
        if (ov < mv || (ov == mv && ol < who)) { mv = ov; who = ol; }
      }
      if (lane == 0) {
        out[q * K_TOP + r] = sqrtf(__uint_as_float((unsigned)(mv >> 32)));
        out[NQ * K_TOP + q * K_TOP + r] = (float)(unsigned)(mv & 0xFFFFFFFFu);
      }
      if (lane == who) e = ~0ULL;
    }
  }
}

// ----------------------------------------------------------------- launcher
extern "C" void kernel_launch(void* const* d_in, const int* in_sizes, int n_in,
                              void* d_out, int out_size, void* d_ws, size_t ws_size,
                              hipStream_t stream) {
  const float* query  = (const float*)d_in[0];
  const float* stored = (const float*)d_in[1];
  const float* resil  = (const float*)d_in[2];
  const float* W      = (const float*)d_in[3];
  const float* M      = (const float*)d_in[4];

  char* ws = (char*)d_ws;
  size_t off = 0;
  float* G    = (float*)(ws + off); off += 16384;
  float* qGT  = (float*)(ws + off); off += 262144;   // [64][1024] f32
  float* qGr  = (float*)(ws + off); off += 262144;   // [1024][64] f32
  unsigned short* qGh = (unsigned short*)(ws + off); off += 131072;  // bf16
  float* q2   = (float*)(ws + off); off += 4096;
  float* qe   = (float*)(ws + off); off += 4096;
  float* tau  = (float*)(ws + off); off += 4096;
  float4* aux4 = (float4*)(ws + off); off += (size_t)NS * 16;  // 2 MB
  int*   ccnt = (int*)(ws + off);   off += (size_t)NQ * NCH * 4;  // 512 KB
  int*   ovcnt = (int*)(ws + off);  off += 4096;
  unsigned int* ovf = (unsigned int*)(ws + off); off += OVCAP * 4;  // 256 KB
  unsigned short* sh = (unsigned short*)(ws + off); off += 16777216;  // bf16 rows
  u64t* cand = (u64t*)(ws + off);   // [NQ][NCH][SLOTS] u64 = 24 MB
  float* skeys = (float*)cand;      // overlay (first 8 MB, used before cand)

  float* out = (float*)d_out;

  hipMemsetAsync(ovcnt, 0, 4096, stream);
  g_kernel<<<16, 256, 0, stream>>>(M, G);
  q_kernel<<<NQ / 4, 256, 0, stream>>>(query, W, G, qGT, qGr, qGh, q2, qe);
  s_kernel<<<NS / 64, 256, 0, stream>>>(stored, resil, G, aux4, sh);
  sub_kernel<<<dim3(32, 8), 256, 0, stream>>>(stored, qGT, q2, aux4, skeys);
  tau_select<<<NQ, 256, 0, stream>>>(skeys, tau);
  main_mfma<<<dim3(NCH, NQ / 64), 256, 0, stream>>>(sh, qGh, q2, qe, tau, aux4,
                                                    ccnt, ovcnt, ovf, cand);
  final_kernel<<<NQ, 256, 0, stream>>>(cand, ccnt, ovcnt, ovf, qGr, q2,
                                       stored, aux4, out);
}

// Round 17
// 184.701 us; speedup vs baseline: 1.2846x; 1.0636x over previous
//
#include <hip/hip_runtime.h>
#include <stdint.h>

// Problem constants (fixed by the reference)
#define NQ 1024
#define NS 131072
#define DMM 2048
#define DCC 64
#define K_TOP 16
#define EPS_RES_F 1e-8f
#define EPS_SQRT_F 1e-12f
#define EPS_A 0.01f       // bf16 hi-only dot abs-error coeff (rigorous bound ~0.004)

#define NCH 128           // candidate chunks over N
#define CHR (NS / NCH)    // 1024 rows per chunk
#define OVCAP 65536       // global overflow list capacity (rare)
#define SLOTS 24          // per-(q,chunk) candidate slots
#define MTOT (NCH * SLOTS)        // 3072 entries per query
#define EPT (MTOT / 256)          // 12 entries per thread
#define SCAP 3328         // survivor capacity >= MTOT + ovf slack

typedef __attribute__((ext_vector_type(8))) short short8v;  // 8 x bf16
typedef __attribute__((ext_vector_type(4))) float f32x4;
typedef unsigned long long u64t;

__device__ __forceinline__ unsigned short f2bf(float x) {  // RNE f32->bf16
  unsigned u = __float_as_uint(x);
  unsigned r = (u + 0x7FFFu + ((u >> 16) & 1u)) >> 16;
  return (unsigned short)r;
}
// directed bf16 rounding for POSITIVE floats (bounds stay provable)
__device__ __forceinline__ unsigned bf16_down_pos(float x) {
  return __float_as_uint(x) >> 16;
}
__device__ __forceinline__ unsigned bf16_up_pos(float x) {
  const unsigned u = __float_as_uint(x);
  return (u >> 16) + ((u & 0xFFFFu) ? 1u : 0u);
}

__device__ __forceinline__ void gl_lds16(const void* g, void* l) {
  __builtin_amdgcn_global_load_lds(
      (const __attribute__((address_space(1))) unsigned int*)g,
      (__attribute__((address_space(3))) unsigned int*)l, 16, 0, 0);
}

// exact key chain — MUST stay bit-identical to sub_kernel's accumulation
__device__ __forceinline__ float exact_key(const float* __restrict__ stored,
                                           const float* qgl, float q2v,
                                           const float4* __restrict__ aux4, int n) {
  const float4* srow = reinterpret_cast<const float4*>(stored + (size_t)n * DCC);
  float a = 0.f;
#pragma unroll
  for (int kb = 0; kb < 16; ++kb) {
    const float4 qv = *reinterpret_cast<const float4*>(&qgl[4 * kb]);
    const float4 sv = srow[kb];
    a = fmaf(qv.w, sv.w, fmaf(qv.z, sv.z, fmaf(qv.y, sv.y, fmaf(qv.x, sv.x, a))));
  }
  const float4 av = aux4[n];
  const float d2 = fmaf(-2.f, a, q2v + av.x);
  return (fmaxf(d2, 0.f) + EPS_SQRT_F) * av.w;
}

// All lanes of a wave: find the bin containing 0-based `rank` in hist[256]
__device__ __forceinline__ void bin_rank256(const int* hist, int rank, int lane,
                                            int& binOut, int& baseOut, int& totalOut) {
  const int b0 = hist[4 * lane + 0], b1 = hist[4 * lane + 1];
  const int b2 = hist[4 * lane + 2], b3 = hist[4 * lane + 3];
  const int s01 = b0 + b1, s012 = s01 + b2;
  const int s = s012 + b3;
  int inc = s;
#pragma unroll
  for (int off = 1; off < 64; off <<= 1) {
    const int u = __shfl_up(inc, off);
    if (lane >= off) inc += u;
  }
  totalOut = __shfl(inc, 63);
  const int excl = inc - s;
  const bool has = (excl <= rank) && (rank < inc);
  const unsigned long long mask = __ballot(has);
  if (mask == 0ULL) { binOut = -1; baseOut = 0; return; }
  const int who = __ffsll((unsigned long long)mask) - 1;
  const int exclW = __shfl(excl, who);
  const int c0 = __shfl(b0, who);
  const int c01 = __shfl(s01, who);
  const int c012 = __shfl(s012, who);
  const int r = rank - exclW;
  int sub, base;
  if (r < c0) { sub = 0; base = 0; }
  else if (r < c01) { sub = 1; base = c0; }
  else if (r < c012) { sub = 2; base = c01; }
  else { sub = 3; base = c012; }
  binOut = 4 * who + sub;
  baseOut = exclW + base;
}

// ---------------------------------------------------------------- G = M M^T
__global__ __launch_bounds__(256) void g_kernel(const float* __restrict__ M,
                                                float* __restrict__ G) {
  __shared__ __align__(16) float Ml[64 * 66];
  const int t = threadIdx.x;
  for (int p = 0; p < 16; ++p) {
    int i = p * 256 + t;
    Ml[(i >> 6) * 66 + (i & 63)] = M[i];
  }
  __syncthreads();
  const int e = blockIdx.x * 256 + t;
  const int i = e >> 6, j = e & 63;
  float a = 0.f;
#pragma unroll
  for (int k = 0; k < 64; ++k) a = fmaf(Ml[i * 66 + k], Ml[j * 66 + k], a);
  G[e] = a;
}

// ---- FUSED q+s kernel: blocks [0,256) run the q path, [256,2304) the s path.
// Both bodies are BYTE-IDENTICAL to the r9 frozen versions (ordering-critical
// qc chain preserved); only the LDS backing is a union and block ids remapped.
// Rationale: q is 256 blocks (1/CU) latency-bound ~30us, s is 2048 blocks
// ~20us; serial = ~50us, fused = ~max. Union LDS = 50176B (= s's footprint).
__global__ __launch_bounds__(256) void qs_kernel(
    const float* __restrict__ query, const float* __restrict__ W,
    const float* __restrict__ G, float* __restrict__ qGT,
    float* __restrict__ qGr, unsigned short* __restrict__ qGh,
    float* __restrict__ q2o, float* __restrict__ qeo,
    const float* __restrict__ stored, const float* __restrict__ resil,
    float4* __restrict__ aux4o, unsigned short* __restrict__ sho) {
  __shared__ __align__(16) char smem[50176];
  const int t = threadIdx.x;
  if (blockIdx.x < NQ / 4) {
    // ----------------- q path (r9 byte-identical) -----------------
    float (*qs)[DMM] = reinterpret_cast<float (*)[DMM]>(smem);            // 32768
    float (*part)[4][64] = reinterpret_cast<float (*)[4][64]>(smem + 32768); // 4096
    float (*qc)[64] = reinterpret_cast<float (*)[64]>(smem + 36864);      // 1024
    const int qb = blockIdx.x * 4;
    {
      const float4* src = reinterpret_cast<const float4*>(query + (size_t)qb * DMM);
      float4* dst = reinterpret_cast<float4*>(&qs[0][0]);
#pragma unroll
      for (int r = 0; r < 8; ++r) dst[r * 256 + t] = src[r * 256 + t];
    }
    __syncthreads();
    const int c = t & 63, seg = t >> 6;
    float p0 = 0.f, p1 = 0.f, p2 = 0.f, p3 = 0.f;
    const int kbase = seg * 512;
    for (int ki = 0; ki < 512; ++ki) {
      const int k = kbase + ki;
      const float w = W[(size_t)k * 64 + c];
      p0 = fmaf(qs[0][k], w, p0);
      p1 = fmaf(qs[1][k], w, p1);
      p2 = fmaf(qs[2][k], w, p2);
      p3 = fmaf(qs[3][k], w, p3);
    }
    part[0][seg][c] = p0; part[1][seg][c] = p1;
    part[2][seg][c] = p2; part[3][seg][c] = p3;
    __syncthreads();
    {
      const int q = t >> 6, cc = t & 63;
      qc[q][cc] = part[q][0][cc] + part[q][1][cc] + part[q][2][cc] + part[q][3][cc];
    }
    __syncthreads();
    const int w = t >> 6, lane = t & 63;
    float g = 0.f;
    for (int j = 0; j < 64; ++j) g = fmaf(qc[w][j], G[j * 64 + lane], g);
    const int q = qb + w;
    qGT[(size_t)lane * NQ + q] = g;
    qGr[(size_t)q * DCC + lane] = g;
    qGh[(size_t)q * DCC + lane] = f2bf(g);
    float pr = qc[w][lane] * g;
    float pn = g * g;
#pragma unroll
    for (int off = 32; off; off >>= 1) {
      pr += __shfl_xor(pr, off);
      pn += __shfl_xor(pn, off);
    }
    if (lane == 0) {
      q2o[q] = pr;
      qeo[q] = EPS_A * sqrtf(pn);
    }
  } else {
    // ----------------- s path (r9 byte-identical) -----------------
    float* Gl = reinterpret_cast<float*>(smem);               // 16896
    float* sst = reinterpret_cast<float*>(smem + 16896);      // 16384
    float* part2 = reinterpret_cast<float*>(smem + 33280);    // 8448
    float* ps = reinterpret_cast<float*>(smem + 41728);       // 8448
    const int nb = ((int)blockIdx.x - NQ / 4) * 64;
    for (int p = 0; p < 16; ++p) {
      int i = p * 256 + t;
      Gl[(i >> 6) * 66 + (i & 63)] = G[i];
    }
    {
      const float4* src = reinterpret_cast<const float4*>(stored + (size_t)nb * DCC);
      float4* dst = reinterpret_cast<float4*>(sst);
#pragma unroll
      for (int r = 0; r < 4; ++r) dst[r * 256 + t] = src[r * 256 + t];
    }
    __syncthreads();
    const int l = t & 31, tw = t >> 5;
    float acc0[8], acc1[8];
#pragma unroll
    for (int i = 0; i < 8; ++i) { acc0[i] = 0.f; acc1[i] = 0.f; }
    for (int kb = 0; kb < 16; ++kb) {
      const float2 ga0 = *reinterpret_cast<const float2*>(&Gl[(4 * kb + 0) * 66 + 2 * l]);
      const float2 ga1 = *reinterpret_cast<const float2*>(&Gl[(4 * kb + 1) * 66 + 2 * l]);
      const float2 ga2 = *reinterpret_cast<const float2*>(&Gl[(4 * kb + 2) * 66 + 2 * l]);
      const float2 ga3 = *reinterpret_cast<const float2*>(&Gl[(4 * kb + 3) * 66 + 2 * l]);
#pragma unroll
      for (int i = 0; i < 8; ++i) {
        const float4 sv = *reinterpret_cast<const float4*>(&sst[(8 * tw + i) * 64 + 4 * kb]);
        acc0[i] = fmaf(ga3.x, sv.w, fmaf(ga2.x, sv.z, fmaf(ga1.x, sv.y, fmaf(ga0.x, sv.x, acc0[i]))));
        acc1[i] = fmaf(ga3.y, sv.w, fmaf(ga2.y, sv.z, fmaf(ga1.y, sv.y, fmaf(ga0.y, sv.x, acc1[i]))));
      }
    }
#pragma unroll
    for (int i = 0; i < 8; ++i) {
      const int n = 8 * tw + i;
      const float2 sj = *reinterpret_cast<const float2*>(&sst[n * 64 + 2 * l]);
      part2[n * 33 + l] = acc0[i] * sj.x + acc1[i] * sj.y;
      ps[n * 33 + l] = sj.x * sj.x + sj.y * sj.y;
    }
    __syncthreads();
    for (int p = 0; p < 16; ++p) {
      const int i = p * 256 + t;
      const int nl = i >> 6, k = i & 63;
      sho[(size_t)(nb + nl) * DCC + k] = f2bf(sst[nl * 64 + k]);
    }
    if (t < 64) {
      float s = 0.f, sp = 0.f;
#pragma unroll
      for (int u = 0; u < 32; ++u) { s += part2[t * 33 + u]; sp += ps[t * 33 + u]; }
      const float rv = resil[nb + t] + EPS_RES_F;
      const float inv = 1.0f / rv;
      aux4o[nb + t] = make_float4(s, 0.5f * rv * rv, sqrtf(sp), inv * inv);
    }
  }
}

// --------- exact f32 keys for the 1/64 subsample (rows n = 64*j, j<2048)
__global__ __launch_bounds__(256) void sub_kernel(
    const float* __restrict__ stored, const float* __restrict__ qGT,
    const float* __restrict__ q2g, const float4* __restrict__ aux4,
    float* __restrict__ skeys) {
  __shared__ __align__(16) float qg[64 * 128];
  __shared__ __align__(16) float sst[64 * 64];
  __shared__ float s2sub[64];
  __shared__ float ir2sub[64];
  const int t = threadIdx.x;
  const int jb = blockIdx.x * 64;
  const int qbase = blockIdx.y * 128;
  for (int p = 0; p < 32; ++p) {
    const int i = p * 256 + t;
    const int k = i >> 7, qq = i & 127;
    qg[k * 128 + qq] = qGT[(size_t)k * NQ + qbase + qq];
  }
#pragma unroll
  for (int p = 0; p < 4; ++p) {
    const int idx = p * 256 + t;
    const int r = idx >> 4, f4 = idx & 15;
    reinterpret_cast<float4*>(sst)[r * 16 + f4] =
        reinterpret_cast<const float4*>(stored + (size_t)(64 * (jb + r)) * DCC)[f4];
  }
  if (t < 64) {
    const float4 v = aux4[64 * (jb + t)];
    s2sub[t] = v.x;
    ir2sub[t] = v.w;
  }
  __syncthreads();
  const int l = t & 31, tw = t >> 5;
  const int q0 = 4 * l;
  float q2r[4];
#pragma unroll
  for (int qq = 0; qq < 4; ++qq) q2r[qq] = q2g[qbase + q0 + qq];
  float acc[4][8];
#pragma unroll
  for (int qq = 0; qq < 4; ++qq)
#pragma unroll
    for (int i = 0; i < 8; ++i) acc[qq][i] = 0.f;
  for (int kb = 0; kb < 16; ++kb) {
    const float4 qa0 = *reinterpret_cast<const float4*>(&qg[(4 * kb + 0) * 128 + q0]);
    const float4 qa1 = *reinterpret_cast<const float4*>(&qg[(4 * kb + 1) * 128 + q0]);
    const float4 qa2 = *reinterpret_cast<const float4*>(&qg[(4 * kb + 2) * 128 + q0]);
    const float4 qa3 = *reinterpret_cast<const float4*>(&qg[(4 * kb + 3) * 128 + q0]);
#pragma unroll
    for (int i = 0; i < 8; ++i) {
      const float4 sv = *reinterpret_cast<const float4*>(&sst[(8 * tw + i) * 64 + 4 * kb]);
      acc[0][i] = fmaf(qa3.x, sv.w, fmaf(qa2.x, sv.z, fmaf(qa1.x, sv.y, fmaf(qa0.x, sv.x, acc[0][i]))));
      acc[1][i] = fmaf(qa3.y, sv.w, fmaf(qa2.y, sv.z, fmaf(qa1.y, sv.y, fmaf(qa0.y, sv.x, acc[1][i]))));
      acc[2][i] = fmaf(qa3.z, sv.w, fmaf(qa2.z, sv.z, fmaf(qa1.z, sv.y, fmaf(qa0.z, sv.x, acc[2][i]))));
      acc[3][i] = fmaf(qa3.w, sv.w, fmaf(qa2.w, sv.z, fmaf(qa1.w, sv.y, fmaf(qa0.w, sv.x, acc[3][i]))));
    }
  }
#pragma unroll
  for (int i = 0; i < 8; ++i) {
    const int jl = 8 * tw + i;
    const float s2v = s2sub[jl];
    const float ir2v = ir2sub[jl];
#pragma unroll
    for (int qq = 0; qq < 4; ++qq) {
      const float d2 = fmaf(-2.f, acc[qq][i], q2r[qq] + s2v);
      const float key = (fmaxf(d2, 0.f) + EPS_SQRT_F) * ir2v;
      skeys[(size_t)(qbase + q0 + qq) * 2048 + jb + jl] = key;
    }
  }
}

// ---- tau[q] = 16th smallest subsample key (exact), *1.0001 margin
__global__ __launch_bounds__(256) void tau_select(
    const float* __restrict__ skeys, float* __restrict__ tau) {
  __shared__ float lk[256 * 17];
  __shared__ float wkv[4][16];
  const int t = threadIdx.x;
  const int lane = t & 63, w = t >> 6;
  const int q = blockIdx.x;
  float k16[16];
#pragma unroll
  for (int s = 0; s < 16; ++s) k16[s] = 3.0e38f;
  for (int i = t; i < 2048; i += 256) {
    const float key = skeys[(size_t)q * 2048 + i];
    if (key < k16[15]) {
#pragma unroll
      for (int s = 15; s >= 1; --s) {
        const bool dprev = key < k16[s - 1];
        const float nk = dprev ? k16[s - 1] : key;
        if (key < k16[s]) k16[s] = nk;
      }
      if (key < k16[0]) k16[0] = key;
    }
  }
#pragma unroll
  for (int s = 0; s < 16; ++s) lk[t * 17 + s] = k16[s];
  __syncthreads();
  {
    int ptr = 0;
    for (int r = 0; r < K_TOP; ++r) {
      float v = lk[t * 17 + ptr];
      int who = lane;
#pragma unroll
      for (int off = 32; off; off >>= 1) {
        const float ov = __shfl_xor(v, off);
        const int ow = __shfl_xor(who, off);
        if (ov < v || (ov == v && ow < who)) { v = ov; who = ow; }
      }
      if (lane == 0) wkv[w][r] = v;
      if (lane == who) ptr++;
    }
  }
  __syncthreads();
  if (w == 0) {
    float v = wkv[lane >> 4][lane & 15];
    float t16 = 0.f;
    for (int r = 0; r < K_TOP; ++r) {
      float mv = v;
      int who = lane;
#pragma unroll
      for (int off = 32; off; off >>= 1) {
        const float ov = __shfl_xor(mv, off);
        const int ow = __shfl_xor(who, off);
        if (ov < mv || (ov == mv && ow < who)) { mv = ov; who = ow; }
      }
      t16 = mv;
      if (lane == who) v = 3.0e38f;
    }
    if (lane == 0) tau[q] = t16 * 1.0001f;
  }
}

// --------------- MFMA screening pass: bf16-hi cross-GEMM + bounded filter
// PROVEN OPTIMUM CONFIG (r9/r14/r16: 72.5us): LDS-staged A tile, (256,4),
// hoisted loop-invariant B fragments. (256,5)/(256,8) SPILL (unified
// VGPR+AGPR file); direct-load = 86us; dbuf = 73.4us. FROZEN.
// stores u64: [63:48] bf16-UP upper key, [47:32] bf16-DOWN lower key, [31:0] n
__global__ __launch_bounds__(256, 4) void main_mfma(
    const unsigned short* __restrict__ sh, const unsigned short* __restrict__ qGh,
    const float* __restrict__ q2g, const float* __restrict__ qeg,
    const float* __restrict__ taug, const float4* __restrict__ aux4,
    int* __restrict__ ccnt, int* __restrict__ ovcnt,
    unsigned int* __restrict__ ovf, u64t* __restrict__ cand) {
  __shared__ __align__(16) char smA[16384];    // 128 n-rows x 128B, XOR-swizzled
  __shared__ __align__(16) float4 auxl[128];   // per-row {s2,h,sn,ir2}
  __shared__ int cnt64[64];
  const int t = threadIdx.x;
  const int lane = t & 63, w = t >> 6;
  const int l15 = lane & 15, hi4 = (lane >> 4) << 2;
  const int chunk = blockIdx.x;    // 0..127 ; linear%8 == chunk%8 -> XCD pinned
  const int qbase = blockIdx.y * 64;
  const int sx = ((lane & 7) << 4) ^ ((lane >> 3) << 4);
  const int g16 = (lane >> 4) << 4;
  const int swz = (lane & 7) << 4;

  if (t < 64) cnt64[t] = 0;
  float q2h_r[4], tau_r[4], qe_r[4];
#pragma unroll
  for (int qi = 0; qi < 4; ++qi) {
    const int q = qbase + qi * 16 + l15;
    q2h_r[qi] = 0.5f * q2g[q];
    tau_r[qi] = taug[q];
    qe_r[qi] = qeg[q];
  }
  // hoisted B fragments (loop-invariant): bfr[kh][qi]
  short8v bfr[2][4];
#pragma unroll
  for (int kh = 0; kh < 2; ++kh)
#pragma unroll
    for (int qi = 0; qi < 4; ++qi)
      bfr[kh][qi] = *reinterpret_cast<const short8v*>(
          (const char*)qGh + (((size_t)(qbase + qi * 16 + l15)) << 7) + (kh << 6) + g16);
  const f32x4 z4 = {0.f, 0.f, 0.f, 0.f};

  for (int nt = 0; nt < 8; ++nt) {
    const int nb = chunk * CHR + nt * 128;
    __syncthreads();  // previous tile fully consumed
#pragma unroll
    for (int ii = 0; ii < 4; ++ii) {
      const int row = w * 32 + ii * 8 + (lane >> 3);
      gl_lds16((const char*)sh + (size_t)(nb + row) * 128 + sx,
               smA + w * 4096 + ii * 1024);
    }
    if (t < 128) auxl[t] = aux4[nb + t];
    __syncthreads();  // drains vmcnt (global_load_lds) + lds writes

    f32x4 acc[2][4];
#pragma unroll
    for (int kh = 0; kh < 2; ++kh) {
      const int kx = ((kh << 6) | g16) ^ swz;
#pragma unroll
      for (int ni = 0; ni < 2; ++ni) {
        const short8v af = *reinterpret_cast<const short8v*>(
            smA + ((w * 32 + ni * 16 + l15) << 7) + kx);
#pragma unroll
        for (int qi = 0; qi < 4; ++qi)
          acc[ni][qi] = (kh == 0)
              ? __builtin_amdgcn_mfma_f32_16x16x32_bf16(af, bfr[0][qi], z4, 0, 0, 0)
              : __builtin_amdgcn_mfma_f32_16x16x32_bf16(af, bfr[1][qi], acc[ni][qi], 0, 0, 0);
      }
    }
    // epilogue: C/D map col(q)=lane&15, row(n)=(lane>>4)*4+reg
#pragma unroll
    for (int ni = 0; ni < 2; ++ni) {
#pragma unroll
      for (int r = 0; r < 4; ++r) {
        const int nl = w * 32 + ni * 16 + hi4 + r;
        const float4 av = auxl[nl];  // {s2, h, sn, ir2}
#pragma unroll
        for (int qi = 0; qi < 4; ++qi) {
          const float a = acc[ni][qi][r];
          const float t1 = fmaf(0.5f, av.x, q2h_r[qi]);
          const float thr = fmaf(-qe_r[qi], av.z, fmaf(-tau_r[qi], av.y, t1));
          if (a >= thr) {
            const int ql = qi * 16 + l15;
            const int n = nb + nl;
            const float d2 = 2.0f * (t1 - a);
            const float keyp = (fmaxf(d2, 0.0f) + EPS_SQRT_F) * av.w;
            const float ev = fmaf(2.0f * qe_r[qi] * av.z, av.w, 1e-5f * keyp) * 1.0002f;
            const unsigned hiw = (bf16_up_pos(keyp + ev) << 16) |
                                 bf16_down_pos(fmaxf(keyp - ev, 0.0f));
            const u64t ce = ((u64t)hiw << 32) | (unsigned)n;
            const int pos = atomicAdd(&cnt64[ql], 1);   // LDS atomic (fast)
            if (pos < SLOTS) {
              cand[((size_t)((qbase + ql) * NCH + chunk)) * SLOTS + pos] = ce;
            } else {
              const int gp = atomicAdd(ovcnt, 1);        // global, rare
              if (gp < OVCAP) ovf[gp] = ((unsigned)(qbase + ql) << 17) | (unsigned)n;
            }
          }
        }
      }
    }
  }
  __syncthreads();
  if (t < 64) {
    int c = cnt64[t];
    if (c > SLOTS) c = SLOTS;
    ccnt[(size_t)(qbase + t) * NCH + chunk] = c;
  }
}

// ------ final: histogram-rank bracket prune + exact refine, 1 block / query
__global__ __launch_bounds__(256) void final_kernel(
    const u64t* __restrict__ cand, const int* __restrict__ ccnt,
    const int* __restrict__ ovcnt, const unsigned int* __restrict__ ovf,
    const float* __restrict__ qGr, const float* __restrict__ q2g,
    const float* __restrict__ stored, const float4* __restrict__ aux4,
    float* __restrict__ out) {
  __shared__ __align__(16) float qgl[64];
  __shared__ int ccl[NCH];
  __shared__ int hist[256];
  __shared__ int scnt;
  __shared__ unsigned int sidx[SCAP];
  __shared__ u64t wku[4][16];
  const int t = threadIdx.x;
  const int lane = t & 63, w = t >> 6;
  const int q = blockIdx.x;
  if (t < 64) qgl[t] = qGr[(size_t)q * DCC + t];
  if (t < NCH) ccl[t] = min(ccnt[(size_t)q * NCH + t], SLOTS);
  hist[t] = 0;
  if (t == 0) scnt = 0;
  __syncthreads();
  u64t ev[EPT];
  unsigned vmask = 0;
  {
    const u64t* base = cand + (size_t)q * NCH * SLOTS;
#pragma unroll
    for (int p = 0; p < EPT; ++p) {
      const int i = p * 256 + t;
      ev[p] = base[i];
      const int seg = i / SLOTS;
      const int j = i - seg * SLOTS;
      if (j < ccl[seg]) vmask |= 1u << p;
    }
  }
#pragma unroll
  for (int p = 0; p < EPT; ++p)
    if (vmask & (1u << p)) atomicAdd(&hist[(int)(ev[p] >> 56)], 1);
  __syncthreads();
  int B, baseB, total;
  bin_rank256(hist, K_TOP - 1, lane, B, baseB, total);
  unsigned U16bits = 0xFFFFu;
  __syncthreads();
  if (total >= K_TOP) {
    hist[t] = 0;
    __syncthreads();
#pragma unroll
    for (int p = 0; p < EPT; ++p)
      if ((vmask & (1u << p)) && (int)(ev[p] >> 56) == B)
        atomicAdd(&hist[(int)((ev[p] >> 48) & 0xFF)], 1);
    __syncthreads();
    int b2, dummy, tot2;
    bin_rank256(hist, K_TOP - 1 - baseB, lane, b2, dummy, tot2);
    U16bits = ((unsigned)B << 8) | (unsigned)b2;
  }
#pragma unroll
  for (int p = 0; p < EPT; ++p) {
    if ((vmask & (1u << p)) && ((unsigned)(ev[p] >> 32) & 0xFFFFu) <= U16bits) {
      const int pos = atomicAdd(&scnt, 1);
      if (pos < SCAP) sidx[pos] = (unsigned)ev[p];
    }
  }
  {
    int oc = *ovcnt;
    if (oc > OVCAP) oc = OVCAP;
    for (int i = t; i < oc; i += 256) {
      const unsigned pk = ovf[i];
      if ((int)(pk >> 17) == q) {
        const int pos = atomicAdd(&scnt, 1);
        if (pos < SCAP) sidx[pos] = pk & 0x1FFFFu;
      }
    }
  }
  __syncthreads();
  int sc = scnt;
  if (sc > SCAP) sc = SCAP;
  const float q2v = q2g[q];
  u64t k16u[16];
#pragma unroll
  for (int s = 0; s < 16; ++s) k16u[s] = ~0ULL;
  for (int i = t; i < sc; i += 256) {
    const int n = (int)sidx[i];
    const u64t pv =
        ((u64t)__float_as_uint(exact_key(stored, qgl, q2v, aux4, n)) << 32) | (unsigned)n;
    if (pv < k16u[15]) {
#pragma unroll
      for (int s = 15; s >= 1; --s) {
        const bool dprev = pv < k16u[s - 1];
        const u64t nk = dprev ? k16u[s - 1] : pv;
        if (pv < k16u[s]) k16u[s] = nk;
      }
      if (pv < k16u[0]) k16u[0] = pv;
    }
  }
  {
    int ptr = 0;
    for (int r = 0; r < K_TOP; ++r) {
      u64t v = k16u[ptr];
      int who = lane;
#pragma unroll
      for (int off = 32; off; off >>= 1) {
        const u64t ov = __shfl_xor(v, off);
        const int ol = __shfl_xor(who, off);
        if (ov < v || (ov == v && ol < who)) { v = ov; who = ol; }
      }
      if (lane == 0) wku[w][r] = v;
      if (lane == who) ptr++;
    }
  }
  __syncthreads();
  if (w == 0) {
    u64t e = wku[lane >> 4][lane & 15];
    for (int r = 0; r < K_TOP; ++r) {
      u64t mv = e;
      int who = lane;
#pragma unroll
      for (int off = 32; off; off >>= 1) {
        const u64t ov = __shfl_xor(mv, off);
        const int ol = __shfl_xor(who, off);
        if (ov < mv || (ov == mv && ol < who)) { mv = ov; who = ol; }
      }
      if (lane == 0) {
        out[q * K_TOP + r] = sqrtf(__uint_as_float((unsigned)(mv >> 32)));
        out[NQ * K_TOP + q * K_TOP + r] = (float)(unsigned)(mv & 0xFFFFFFFFu);
      }
      if (lane == who) e = ~0ULL;
    }
  }
}

// ----------------------------------------------------------------- launcher
extern "C" void kernel_launch(void* const* d_in, const int* in_sizes, int n_in,
                              void* d_out, int out_size, void* d_ws, size_t ws_size,
                              hipStream_t stream) {
  const float* query  = (const float*)d_in[0];
  const float* stored = (const float*)d_in[1];
  const float* resil  = (const float*)d_in[2];
  const float* W      = (const float*)d_in[3];
  const float* M      = (const float*)d_in[4];

  char* ws = (char*)d_ws;
  size_t off = 0;
  float* G    = (float*)(ws + off); off += 16384;
  float* qGT  = (float*)(ws + off); off += 262144;   // [64][1024] f32
  float* qGr  = (float*)(ws + off); off += 262144;   // [1024][64] f32
  unsigned short* qGh = (unsigned short*)(ws + off); off += 131072;  // bf16
  float* q2   = (float*)(ws + off); off += 4096;
  float* qe   = (float*)(ws + off); off += 4096;
  float* tau  = (float*)(ws + off); off += 4096;
  float4* aux4 = (float4*)(ws + off); off += (size_t)NS * 16;  // 2 MB
  int*   ccnt = (int*)(ws + off);   off += (size_t)NQ * NCH * 4;  // 512 KB
  int*   ovcnt = (int*)(ws + off);  off += 4096;
  unsigned int* ovf = (unsigned int*)(ws + off); off += OVCAP * 4;  // 256 KB
  unsigned short* sh = (unsigned short*)(ws + off); off += 16777216;  // bf16 rows
  u64t* cand = (u64t*)(ws + off);   // [NQ][NCH][SLOTS] u64 = 24 MB
  float* skeys = (float*)cand;      // overlay (first 8 MB, used before cand)

  float* out = (float*)d_out;

  hipMemsetAsync(ovcnt, 0, 4096, stream);
  g_kernel<<<16, 256, 0, stream>>>(M, G);
  qs_kernel<<<NQ / 4 + NS / 64, 256, 0, stream>>>(query, W, G, qGT, qGr, qGh,
                                                  q2, qe, stored, resil, aux4, sh);
  sub_kernel<<<dim3(32, 8), 256, 0, stream>>>(stored, qGT, q2, aux4, skeys);
  tau_select<<<NQ, 256, 0, stream>>>(skeys, tau);
  main_mfma<<<dim3(NCH, NQ / 64), 256, 0, stream>>>(sh, qGh, q2, qe, tau, aux4,
                                                    ccnt, ovcnt, ovf, cand);
  final_kernel<<<NQ, 256, 0, stream>>>(cand, ccnt, ovcnt, ovf, qGr, q2,
                                       stored, aux4, out);
}

// Round 18
// 179.237 us; speedup vs baseline: 1.3238x; 1.0305x over previous
//
#include <hip/hip_runtime.h>
#include <stdint.h>

// Problem constants (fixed by the reference)
#define NQ 1024
#define NS 131072
#define DMM 2048
#define DCC 64
#define K_TOP 16
#define EPS_RES_F 1e-8f
#define EPS_SQRT_F 1e-12f
#define EPS_A 0.01f       // bf16 hi-only dot abs-error coeff (rigorous bound ~0.004)

#define NCH 128           // candidate chunks over N
#define CHR (NS / NCH)    // 1024 rows per chunk
#define OVCAP 65536       // global overflow list capacity (rare)
#define SLOTS 24          // per-(q,chunk) candidate slots
#define MTOT (NCH * SLOTS)        // 3072 entries per query
#define EPT (MTOT / 256)          // 12 entries per thread
#define SCAP 3328         // survivor capacity >= MTOT + ovf slack

typedef __attribute__((ext_vector_type(8))) short short8v;  // 8 x bf16
typedef __attribute__((ext_vector_type(4))) float f32x4;
typedef unsigned long long u64t;

__device__ __forceinline__ unsigned short f2bf(float x) {  // RNE f32->bf16
  unsigned u = __float_as_uint(x);
  unsigned r = (u + 0x7FFFu + ((u >> 16) & 1u)) >> 16;
  return (unsigned short)r;
}
// directed bf16 rounding for POSITIVE floats (bounds stay provable)
__device__ __forceinline__ unsigned bf16_down_pos(float x) {
  return __float_as_uint(x) >> 16;
}
__device__ __forceinline__ unsigned bf16_up_pos(float x) {
  const unsigned u = __float_as_uint(x);
  return (u >> 16) + ((u & 0xFFFFu) ? 1u : 0u);
}

__device__ __forceinline__ void gl_lds16(const void* g, void* l) {
  __builtin_amdgcn_global_load_lds(
      (const __attribute__((address_space(1))) unsigned int*)g,
      (__attribute__((address_space(3))) unsigned int*)l, 16, 0, 0);
}

// exact key chain — MUST stay bit-identical to sub_kernel's accumulation
__device__ __forceinline__ float exact_key(const float* __restrict__ stored,
                                           const float* qgl, float q2v,
                                           const float4* __restrict__ aux4, int n) {
  const float4* srow = reinterpret_cast<const float4*>(stored + (size_t)n * DCC);
  float a = 0.f;
#pragma unroll
  for (int kb = 0; kb < 16; ++kb) {
    const float4 qv = *reinterpret_cast<const float4*>(&qgl[4 * kb]);
    const float4 sv = srow[kb];
    a = fmaf(qv.w, sv.w, fmaf(qv.z, sv.z, fmaf(qv.y, sv.y, fmaf(qv.x, sv.x, a))));
  }
  const float4 av = aux4[n];
  const float d2 = fmaf(-2.f, a, q2v + av.x);
  return (fmaxf(d2, 0.f) + EPS_SQRT_F) * av.w;
}

// All lanes of a wave: find the bin containing 0-based `rank` in hist[256]
__device__ __forceinline__ void bin_rank256(const int* hist, int rank, int lane,
                                            int& binOut, int& baseOut, int& totalOut) {
  const int b0 = hist[4 * lane + 0], b1 = hist[4 * lane + 1];
  const int b2 = hist[4 * lane + 2], b3 = hist[4 * lane + 3];
  const int s01 = b0 + b1, s012 = s01 + b2;
  const int s = s012 + b3;
  int inc = s;
#pragma unroll
  for (int off = 1; off < 64; off <<= 1) {
    const int u = __shfl_up(inc, off);
    if (lane >= off) inc += u;
  }
  totalOut = __shfl(inc, 63);
  const int excl = inc - s;
  const bool has = (excl <= rank) && (rank < inc);
  const unsigned long long mask = __ballot(has);
  if (mask == 0ULL) { binOut = -1; baseOut = 0; return; }
  const int who = __ffsll((unsigned long long)mask) - 1;
  const int exclW = __shfl(excl, who);
  const int c0 = __shfl(b0, who);
  const int c01 = __shfl(s01, who);
  const int c012 = __shfl(s012, who);
  const int r = rank - exclW;
  int sub, base;
  if (r < c0) { sub = 0; base = 0; }
  else if (r < c01) { sub = 1; base = c0; }
  else if (r < c012) { sub = 2; base = c01; }
  else { sub = 3; base = c012; }
  binOut = 4 * who + sub;
  baseOut = exclW + base;
}

// ---------------------------------------------------------------- G = M M^T
__global__ __launch_bounds__(256) void g_kernel(const float* __restrict__ M,
                                                float* __restrict__ G) {
  __shared__ __align__(16) float Ml[64 * 66];
  const int t = threadIdx.x;
  for (int p = 0; p < 16; ++p) {
    int i = p * 256 + t;
    Ml[(i >> 6) * 66 + (i & 63)] = M[i];
  }
  __syncthreads();
  const int e = blockIdx.x * 256 + t;
  const int i = e >> 6, j = e & 63;
  float a = 0.f;
#pragma unroll
  for (int k = 0; k < 64; ++k) a = fmaf(Ml[i * 66 + k], Ml[j * 66 + k], a);
  G[e] = a;
}

// ---- FUSED q+s kernel (r17 proven: -12us): blocks [0,256) q path,
// [256,2304) s path. Bodies BYTE-IDENTICAL to r9 frozen versions.
__global__ __launch_bounds__(256) void qs_kernel(
    const float* __restrict__ query, const float* __restrict__ W,
    const float* __restrict__ G, float* __restrict__ qGT,
    float* __restrict__ qGr, unsigned short* __restrict__ qGh,
    float* __restrict__ q2o, float* __restrict__ qeo,
    const float* __restrict__ stored, const float* __restrict__ resil,
    float4* __restrict__ aux4o, unsigned short* __restrict__ sho) {
  __shared__ __align__(16) char smem[50176];
  const int t = threadIdx.x;
  if (blockIdx.x < NQ / 4) {
    // ----------------- q path (r9 byte-identical) -----------------
    float (*qs)[DMM] = reinterpret_cast<float (*)[DMM]>(smem);            // 32768
    float (*part)[4][64] = reinterpret_cast<float (*)[4][64]>(smem + 32768); // 4096
    float (*qc)[64] = reinterpret_cast<float (*)[64]>(smem + 36864);      // 1024
    const int qb = blockIdx.x * 4;
    {
      const float4* src = reinterpret_cast<const float4*>(query + (size_t)qb * DMM);
      float4* dst = reinterpret_cast<float4*>(&qs[0][0]);
#pragma unroll
      for (int r = 0; r < 8; ++r) dst[r * 256 + t] = src[r * 256 + t];
    }
    __syncthreads();
    const int c = t & 63, seg = t >> 6;
    float p0 = 0.f, p1 = 0.f, p2 = 0.f, p3 = 0.f;
    const int kbase = seg * 512;
    for (int ki = 0; ki < 512; ++ki) {
      const int k = kbase + ki;
      const float w = W[(size_t)k * 64 + c];
      p0 = fmaf(qs[0][k], w, p0);
      p1 = fmaf(qs[1][k], w, p1);
      p2 = fmaf(qs[2][k], w, p2);
      p3 = fmaf(qs[3][k], w, p3);
    }
    part[0][seg][c] = p0; part[1][seg][c] = p1;
    part[2][seg][c] = p2; part[3][seg][c] = p3;
    __syncthreads();
    {
      const int q = t >> 6, cc = t & 63;
      qc[q][cc] = part[q][0][cc] + part[q][1][cc] + part[q][2][cc] + part[q][3][cc];
    }
    __syncthreads();
    const int w = t >> 6, lane = t & 63;
    float g = 0.f;
    for (int j = 0; j < 64; ++j) g = fmaf(qc[w][j], G[j * 64 + lane], g);
    const int q = qb + w;
    qGT[(size_t)lane * NQ + q] = g;
    qGr[(size_t)q * DCC + lane] = g;
    qGh[(size_t)q * DCC + lane] = f2bf(g);
    float pr = qc[w][lane] * g;
    float pn = g * g;
#pragma unroll
    for (int off = 32; off; off >>= 1) {
      pr += __shfl_xor(pr, off);
      pn += __shfl_xor(pn, off);
    }
    if (lane == 0) {
      q2o[q] = pr;
      qeo[q] = EPS_A * sqrtf(pn);
    }
  } else {
    // ----------------- s path (r9 byte-identical) -----------------
    float* Gl = reinterpret_cast<float*>(smem);               // 16896
    float* sst = reinterpret_cast<float*>(smem + 16896);      // 16384
    float* part2 = reinterpret_cast<float*>(smem + 33280);    // 8448
    float* ps = reinterpret_cast<float*>(smem + 41728);       // 8448
    const int nb = ((int)blockIdx.x - NQ / 4) * 64;
    for (int p = 0; p < 16; ++p) {
      int i = p * 256 + t;
      Gl[(i >> 6) * 66 + (i & 63)] = G[i];
    }
    {
      const float4* src = reinterpret_cast<const float4*>(stored + (size_t)nb * DCC);
      float4* dst = reinterpret_cast<float4*>(sst);
#pragma unroll
      for (int r = 0; r < 4; ++r) dst[r * 256 + t] = src[r * 256 + t];
    }
    __syncthreads();
    const int l = t & 31, tw = t >> 5;
    float acc0[8], acc1[8];
#pragma unroll
    for (int i = 0; i < 8; ++i) { acc0[i] = 0.f; acc1[i] = 0.f; }
    for (int kb = 0; kb < 16; ++kb) {
      const float2 ga0 = *reinterpret_cast<const float2*>(&Gl[(4 * kb + 0) * 66 + 2 * l]);
      const float2 ga1 = *reinterpret_cast<const float2*>(&Gl[(4 * kb + 1) * 66 + 2 * l]);
      const float2 ga2 = *reinterpret_cast<const float2*>(&Gl[(4 * kb + 2) * 66 + 2 * l]);
      const float2 ga3 = *reinterpret_cast<const float2*>(&Gl[(4 * kb + 3) * 66 + 2 * l]);
#pragma unroll
      for (int i = 0; i < 8; ++i) {
        const float4 sv = *reinterpret_cast<const float4*>(&sst[(8 * tw + i) * 64 + 4 * kb]);
        acc0[i] = fmaf(ga3.x, sv.w, fmaf(ga2.x, sv.z, fmaf(ga1.x, sv.y, fmaf(ga0.x, sv.x, acc0[i]))));
        acc1[i] = fmaf(ga3.y, sv.w, fmaf(ga2.y, sv.z, fmaf(ga1.y, sv.y, fmaf(ga0.y, sv.x, acc1[i]))));
      }
    }
#pragma unroll
    for (int i = 0; i < 8; ++i) {
      const int n = 8 * tw + i;
      const float2 sj = *reinterpret_cast<const float2*>(&sst[n * 64 + 2 * l]);
      part2[n * 33 + l] = acc0[i] * sj.x + acc1[i] * sj.y;
      ps[n * 33 + l] = sj.x * sj.x + sj.y * sj.y;
    }
    __syncthreads();
    for (int p = 0; p < 16; ++p) {
      const int i = p * 256 + t;
      const int nl = i >> 6, k = i & 63;
      sho[(size_t)(nb + nl) * DCC + k] = f2bf(sst[nl * 64 + k]);
    }
    if (t < 64) {
      float s = 0.f, sp = 0.f;
#pragma unroll
      for (int u = 0; u < 32; ++u) { s += part2[t * 33 + u]; sp += ps[t * 33 + u]; }
      const float rv = resil[nb + t] + EPS_RES_F;
      const float inv = 1.0f / rv;
      aux4o[nb + t] = make_float4(s, 0.5f * rv * rv, sqrtf(sp), inv * inv);
    }
  }
}

// --------- exact f32 keys for the 1/64 subsample (rows n = 64*j, j<2048)
__global__ __launch_bounds__(256) void sub_kernel(
    const float* __restrict__ stored, const float* __restrict__ qGT,
    const float* __restrict__ q2g, const float4* __restrict__ aux4,
    float* __restrict__ skeys) {
  __shared__ __align__(16) float qg[64 * 128];
  __shared__ __align__(16) float sst[64 * 64];
  __shared__ float s2sub[64];
  __shared__ float ir2sub[64];
  const int t = threadIdx.x;
  const int jb = blockIdx.x * 64;
  const int qbase = blockIdx.y * 128;
  for (int p = 0; p < 32; ++p) {
    const int i = p * 256 + t;
    const int k = i >> 7, qq = i & 127;
    qg[k * 128 + qq] = qGT[(size_t)k * NQ + qbase + qq];
  }
#pragma unroll
  for (int p = 0; p < 4; ++p) {
    const int idx = p * 256 + t;
    const int r = idx >> 4, f4 = idx & 15;
    reinterpret_cast<float4*>(sst)[r * 16 + f4] =
        reinterpret_cast<const float4*>(stored + (size_t)(64 * (jb + r)) * DCC)[f4];
  }
  if (t < 64) {
    const float4 v = aux4[64 * (jb + t)];
    s2sub[t] = v.x;
    ir2sub[t] = v.w;
  }
  __syncthreads();
  const int l = t & 31, tw = t >> 5;
  const int q0 = 4 * l;
  float q2r[4];
#pragma unroll
  for (int qq = 0; qq < 4; ++qq) q2r[qq] = q2g[qbase + q0 + qq];
  float acc[4][8];
#pragma unroll
  for (int qq = 0; qq < 4; ++qq)
#pragma unroll
    for (int i = 0; i < 8; ++i) acc[qq][i] = 0.f;
  for (int kb = 0; kb < 16; ++kb) {
    const float4 qa0 = *reinterpret_cast<const float4*>(&qg[(4 * kb + 0) * 128 + q0]);
    const float4 qa1 = *reinterpret_cast<const float4*>(&qg[(4 * kb + 1) * 128 + q0]);
    const float4 qa2 = *reinterpret_cast<const float4*>(&qg[(4 * kb + 2) * 128 + q0]);
    const float4 qa3 = *reinterpret_cast<const float4*>(&qg[(4 * kb + 3) * 128 + q0]);
#pragma unroll
    for (int i = 0; i < 8; ++i) {
      const float4 sv = *reinterpret_cast<const float4*>(&sst[(8 * tw + i) * 64 + 4 * kb]);
      acc[0][i] = fmaf(qa3.x, sv.w, fmaf(qa2.x, sv.z, fmaf(qa1.x, sv.y, fmaf(qa0.x, sv.x, acc[0][i]))));
      acc[1][i] = fmaf(qa3.y, sv.w, fmaf(qa2.y, sv.z, fmaf(qa1.y, sv.y, fmaf(qa0.y, sv.x, acc[1][i]))));
      acc[2][i] = fmaf(qa3.z, sv.w, fmaf(qa2.z, sv.z, fmaf(qa1.z, sv.y, fmaf(qa0.z, sv.x, acc[2][i]))));
      acc[3][i] = fmaf(qa3.w, sv.w, fmaf(qa2.w, sv.z, fmaf(qa1.w, sv.y, fmaf(qa0.w, sv.x, acc[3][i]))));
    }
  }
#pragma unroll
  for (int i = 0; i < 8; ++i) {
    const int jl = 8 * tw + i;
    const float s2v = s2sub[jl];
    const float ir2v = ir2sub[jl];
#pragma unroll
    for (int qq = 0; qq < 4; ++qq) {
      const float d2 = fmaf(-2.f, acc[qq][i], q2r[qq] + s2v);
      const float key = (fmaxf(d2, 0.f) + EPS_SQRT_F) * ir2v;
      skeys[(size_t)(qbase + q0 + qq) * 2048 + jb + jl] = key;
    }
  }
}

// ---- tau[q] = 16th smallest subsample key (exact), *1.0001 margin
__global__ __launch_bounds__(256) void tau_select(
    const float* __restrict__ skeys, float* __restrict__ tau) {
  __shared__ float lk[256 * 17];
  __shared__ float wkv[4][16];
  const int t = threadIdx.x;
  const int lane = t & 63, w = t >> 6;
  const int q = blockIdx.x;
  float k16[16];
#pragma unroll
  for (int s = 0; s < 16; ++s) k16[s] = 3.0e38f;
  for (int i = t; i < 2048; i += 256) {
    const float key = skeys[(size_t)q * 2048 + i];
    if (key < k16[15]) {
#pragma unroll
      for (int s = 15; s >= 1; --s) {
        const bool dprev = key < k16[s - 1];
        const float nk = dprev ? k16[s - 1] : key;
        if (key < k16[s]) k16[s] = nk;
      }
      if (key < k16[0]) k16[0] = key;
    }
  }
#pragma unroll
  for (int s = 0; s < 16; ++s) lk[t * 17 + s] = k16[s];
  __syncthreads();
  {
    int ptr = 0;
    for (int r = 0; r < K_TOP; ++r) {
      float v = lk[t * 17 + ptr];
      int who = lane;
#pragma unroll
      for (int off = 32; off; off >>= 1) {
        const float ov = __shfl_xor(v, off);
        const int ow = __shfl_xor(who, off);
        if (ov < v || (ov == v && ow < who)) { v = ov; who = ow; }
      }
      if (lane == 0) wkv[w][r] = v;
      if (lane == who) ptr++;
    }
  }
  __syncthreads();
  if (w == 0) {
    float v = wkv[lane >> 4][lane & 15];
    float t16 = 0.f;
    for (int r = 0; r < K_TOP; ++r) {
      float mv = v;
      int who = lane;
#pragma unroll
      for (int off = 32; off; off >>= 1) {
        const float ov = __shfl_xor(mv, off);
        const int ow = __shfl_xor(who, off);
        if (ov < mv || (ov == mv && ow < who)) { mv = ov; who = ow; }
      }
      t16 = mv;
      if (lane == who) v = 3.0e38f;
    }
    if (lane == 0) tau[q] = t16 * 1.0001f;
  }
}

// --------------- MFMA screening pass: bf16-hi cross-GEMM + bounded filter
// r18 EXPERIMENT: 128n x 32q tile (was 64q) -> acc[2][2]=16 acc regs,
// bfr[2][2]=16 VGPR (both halved) => ~64 total regs/wave, enabling
// __launch_bounds__(256,6): 6 waves/SIMD x ~85-reg budget fits WITHOUT spill.
// Math/candidates identical (append order differs; final select is
// order-invariant). Spill sentinel: FETCH >> 100MB => revert.
// stores u64: [63:48] bf16-UP upper key, [47:32] bf16-DOWN lower key, [31:0] n
__global__ __launch_bounds__(256, 6) void main_mfma(
    const unsigned short* __restrict__ sh, const unsigned short* __restrict__ qGh,
    const float* __restrict__ q2g, const float* __restrict__ qeg,
    const float* __restrict__ taug, const float4* __restrict__ aux4,
    int* __restrict__ ccnt, int* __restrict__ ovcnt,
    unsigned int* __restrict__ ovf, u64t* __restrict__ cand) {
  __shared__ __align__(16) char smA[16384];    // 128 n-rows x 128B, XOR-swizzled
  __shared__ __align__(16) float4 auxl[128];   // per-row {s2,h,sn,ir2}
  __shared__ int cnt32[32];
  const int t = threadIdx.x;
  const int lane = t & 63, w = t >> 6;
  const int l15 = lane & 15, hi4 = (lane >> 4) << 2;
  const int chunk = blockIdx.x;    // 0..127 ; linear%8 == chunk%8 -> XCD pinned
  const int qbase = blockIdx.y * 32;
  const int sx = ((lane & 7) << 4) ^ ((lane >> 3) << 4);
  const int g16 = (lane >> 4) << 4;
  const int swz = (lane & 7) << 4;

  if (t < 32) cnt32[t] = 0;
  float q2h_r[2], tau_r[2], qe_r[2];
#pragma unroll
  for (int qi = 0; qi < 2; ++qi) {
    const int q = qbase + qi * 16 + l15;
    q2h_r[qi] = 0.5f * q2g[q];
    tau_r[qi] = taug[q];
    qe_r[qi] = qeg[q];
  }
  // hoisted B fragments (loop-invariant): bfr[kh][qi]
  short8v bfr[2][2];
#pragma unroll
  for (int kh = 0; kh < 2; ++kh)
#pragma unroll
    for (int qi = 0; qi < 2; ++qi)
      bfr[kh][qi] = *reinterpret_cast<const short8v*>(
          (const char*)qGh + (((size_t)(qbase + qi * 16 + l15)) << 7) + (kh << 6) + g16);
  const f32x4 z4 = {0.f, 0.f, 0.f, 0.f};

  for (int nt = 0; nt < 8; ++nt) {
    const int nb = chunk * CHR + nt * 128;
    __syncthreads();  // previous tile fully consumed
#pragma unroll
    for (int ii = 0; ii < 4; ++ii) {
      const int row = w * 32 + ii * 8 + (lane >> 3);
      gl_lds16((const char*)sh + (size_t)(nb + row) * 128 + sx,
               smA + w * 4096 + ii * 1024);
    }
    if (t < 128) auxl[t] = aux4[nb + t];
    __syncthreads();  // drains vmcnt (global_load_lds) + lds writes

    f32x4 acc[2][2];
#pragma unroll
    for (int kh = 0; kh < 2; ++kh) {
      const int kx = ((kh << 6) | g16) ^ swz;
#pragma unroll
      for (int ni = 0; ni < 2; ++ni) {
        const short8v af = *reinterpret_cast<const short8v*>(
            smA + ((w * 32 + ni * 16 + l15) << 7) + kx);
#pragma unroll
        for (int qi = 0; qi < 2; ++qi)
          acc[ni][qi] = (kh == 0)
              ? __builtin_amdgcn_mfma_f32_16x16x32_bf16(af, bfr[0][qi], z4, 0, 0, 0)
              : __builtin_amdgcn_mfma_f32_16x16x32_bf16(af, bfr[1][qi], acc[ni][qi], 0, 0, 0);
      }
    }
    // epilogue: C/D map col(q)=lane&15, row(n)=(lane>>4)*4+reg
#pragma unroll
    for (int ni = 0; ni < 2; ++ni) {
#pragma unroll
      for (int r = 0; r < 4; ++r) {
        const int nl = w * 32 + ni * 16 + hi4 + r;
        const float4 av = auxl[nl];  // {s2, h, sn, ir2}
#pragma unroll
        for (int qi = 0; qi < 2; ++qi) {
          const float a = acc[ni][qi][r];
          const float t1 = fmaf(0.5f, av.x, q2h_r[qi]);
          const float thr = fmaf(-qe_r[qi], av.z, fmaf(-tau_r[qi], av.y, t1));
          if (a >= thr) {
            const int ql = qi * 16 + l15;
            const int n = nb + nl;
            const float d2 = 2.0f * (t1 - a);
            const float keyp = (fmaxf(d2, 0.0f) + EPS_SQRT_F) * av.w;
            const float ev = fmaf(2.0f * qe_r[qi] * av.z, av.w, 1e-5f * keyp) * 1.0002f;
            const unsigned hiw = (bf16_up_pos(keyp + ev) << 16) |
                                 bf16_down_pos(fmaxf(keyp - ev, 0.0f));
            const u64t ce = ((u64t)hiw << 32) | (unsigned)n;
            const int pos = atomicAdd(&cnt32[ql], 1);   // LDS atomic (fast)
            if (pos < SLOTS) {
              cand[((size_t)((qbase + ql) * NCH + chunk)) * SLOTS + pos] = ce;
            } else {
              const int gp = atomicAdd(ovcnt, 1);        // global, rare
              if (gp < OVCAP) ovf[gp] = ((unsigned)(qbase + ql) << 17) | (unsigned)n;
            }
          }
        }
      }
    }
  }
  __syncthreads();
  if (t < 32) {
    int c = cnt32[t];
    if (c > SLOTS) c = SLOTS;
    ccnt[(size_t)(qbase + t) * NCH + chunk] = c;
  }
}

// ------ final: histogram-rank bracket prune + exact refine, 1 block / query
__global__ __launch_bounds__(256) void final_kernel(
    const u64t* __restrict__ cand, const int* __restrict__ ccnt,
    const int* __restrict__ ovcnt, const unsigned int* __restrict__ ovf,
    const float* __restrict__ qGr, const float* __restrict__ q2g,
    const float* __restrict__ stored, const float4* __restrict__ aux4,
    float* __restrict__ out) {
  __shared__ __align__(16) float qgl[64];
  __shared__ int ccl[NCH];
  __shared__ int hist[256];
  __shared__ int scnt;
  __shared__ unsigned int sidx[SCAP];
  __shared__ u64t wku[4][16];
  const int t = threadIdx.x;
  const int lane = t & 63, w = t >> 6;
  const int q = blockIdx.x;
  if (t < 64) qgl[t] = qGr[(size_t)q * DCC + t];
  if (t < NCH) ccl[t] = min(ccnt[(size_t)q * NCH + t], SLOTS);
  hist[t] = 0;
  if (t == 0) scnt = 0;
  __syncthreads();
  u64t ev[EPT];
  unsigned vmask = 0;
  {
    const u64t* base = cand + (size_t)q * NCH * SLOTS;
#pragma unroll
    for (int p = 0; p < EPT; ++p) {
      const int i = p * 256 + t;
      ev[p] = base[i];
      const int seg = i / SLOTS;
      const int j = i - seg * SLOTS;
      if (j < ccl[seg]) vmask |= 1u << p;
    }
  }
#pragma unroll
  for (int p = 0; p < EPT; ++p)
    if (vmask & (1u << p)) atomicAdd(&hist[(int)(ev[p] >> 56)], 1);
  __syncthreads();
  int B, baseB, total;
  bin_rank256(hist, K_TOP - 1, lane, B, baseB, total);
  unsigned U16bits = 0xFFFFu;
  __syncthreads();
  if (total >= K_TOP) {
    hist[t] = 0;
    __syncthreads();
#pragma unroll
    for (int p = 0; p < EPT; ++p)
      if ((vmask & (1u << p)) && (int)(ev[p] >> 56) == B)
        atomicAdd(&hist[(int)((ev[p] >> 48) & 0xFF)], 1);
    __syncthreads();
    int b2, dummy, tot2;
    bin_rank256(hist, K_TOP - 1 - baseB, lane, b2, dummy, tot2);
    U16bits = ((unsigned)B << 8) | (unsigned)b2;
  }
#pragma unroll
  for (int p = 0; p < EPT; ++p) {
    if ((vmask & (1u << p)) && ((unsigned)(ev[p] >> 32) & 0xFFFFu) <= U16bits) {
      const int pos = atomicAdd(&scnt, 1);
      if (pos < SCAP) sidx[pos] = (unsigned)ev[p];
    }
  }
  {
    int oc = *ovcnt;
    if (oc > OVCAP) oc = OVCAP;
    for (int i = t; i < oc; i += 256) {
      const unsigned pk = ovf[i];
      if ((int)(pk >> 17) == q) {
        const int pos = atomicAdd(&scnt, 1);
        if (pos < SCAP) sidx[pos] = pk & 0x1FFFFu;
      }
    }
  }
  __syncthreads();
  int sc = scnt;
  if (sc > SCAP) sc = SCAP;
  const float q2v = q2g[q];
  u64t k16u[16];
#pragma unroll
  for (int s = 0; s < 16; ++s) k16u[s] = ~0ULL;
  for (int i = t; i < sc; i += 256) {
    const int n = (int)sidx[i];
    const u64t pv =
        ((u64t)__float_as_uint(exact_key(stored, qgl, q2v, aux4, n)) << 32) | (unsigned)n;
    if (pv < k16u[15]) {
#pragma unroll
      for (int s = 15; s >= 1; --s) {
        const bool dprev = pv < k16u[s - 1];
        const u64t nk = dprev ? k16u[s - 1] : pv;
        if (pv < k16u[s]) k16u[s] = nk;
      }
      if (pv < k16u[0]) k16u[0] = pv;
    }
  }
  {
    int ptr = 0;
    for (int r = 0; r < K_TOP; ++r) {
      u64t v = k16u[ptr];
      int who = lane;
#pragma unroll
      for (int off = 32; off; off >>= 1) {
        const u64t ov = __shfl_xor(v, off);
        const int ol = __shfl_xor(who, off);
        if (ov < v || (ov == v && ol < who)) { v = ov; who = ol; }
      }
      if (lane == 0) wku[w][r] = v;
      if (lane == who) ptr++;
    }
  }
  __syncthreads();
  if (w == 0) {
    u64t e = wku[lane >> 4][lane & 15];
    for (int r = 0; r < K_TOP; ++r) {
      u64t mv = e;
      int who = lane;
#pragma unroll
      for (int off = 32; off; off >>= 1) {
        const u64t ov = __shfl_xor(mv, off);
        const int ol = __shfl_xor(who, off);
        if (ov < mv || (ov == mv && ol < who)) { mv = ov; who = ol; }
      }
      if (lane == 0) {
        out[q * K_TOP + r] = sqrtf(__uint_as_float((unsigned)(mv >> 32)));
        out[NQ * K_TOP + q * K_TOP + r] = (float)(unsigned)(mv & 0xFFFFFFFFu);
      }
      if (lane == who) e = ~0ULL;
    }
  }
}

// ----------------------------------------------------------------- launcher
extern "C" void kernel_launch(void* const* d_in, const int* in_sizes, int n_in,
                              void* d_out, int out_size, void* d_ws, size_t ws_size,
                              hipStream_t stream) {
  const float* query  = (const float*)d_in[0];
  const float* stored = (const float*)d_in[1];
  const float* resil  = (const float*)d_in[2];
  const float* W      = (const float*)d_in[3];
  const float* M      = (const float*)d_in[4];

  char* ws = (char*)d_ws;
  size_t off = 0;
  float* G    = (float*)(ws + off); off += 16384;
  float* qGT  = (float*)(ws + off); off += 262144;   // [64][1024] f32
  float* qGr  = (float*)(ws + off); off += 262144;   // [1024][64] f32
  unsigned short* qGh = (unsigned short*)(ws + off); off += 131072;  // bf16
  float* q2   = (float*)(ws + off); off += 4096;
  float* qe   = (float*)(ws + off); off += 4096;
  float* tau  = (float*)(ws + off); off += 4096;
  float4* aux4 = (float4*)(ws + off); off += (size_t)NS * 16;  // 2 MB
  int*   ccnt = (int*)(ws + off);   off += (size_t)NQ * NCH * 4;  // 512 KB
  int*   ovcnt = (int*)(ws + off);  off += 4096;
  unsigned int* ovf = (unsigned int*)(ws + off); off += OVCAP * 4;  // 256 KB
  unsigned short* sh = (unsigned short*)(ws + off); off += 16777216;  // bf16 rows
  u64t* cand = (u64t*)(ws + off);   // [NQ][NCH][SLOTS] u64 = 24 MB
  float* skeys = (float*)cand;      // overlay (first 8 MB, used before cand)

  float* out = (float*)d_out;

  hipMemsetAsync(ovcnt, 0, 4096, stream);
  g_kernel<<<16, 256, 0, stream>>>(M, G);
  qs_kernel<<<NQ / 4 + NS / 64, 256, 0, stream>>>(query, W, G, qGT, qGr, qGh,
                                                  q2, qe, stored, resil, aux4, sh);
  sub_kernel<<<dim3(32, 8), 256, 0, stream>>>(stored, qGT, q2, aux4, skeys);
  tau_select<<<NQ, 256, 0, stream>>>(skeys, tau);
  main_mfma<<<dim3(NCH, NQ / 32), 256, 0, stream>>>(sh, qGh, q2, qe, tau, aux4,
                                                    ccnt, ovcnt, ovf, cand);
  final_kernel<<<NQ, 256, 0, stream>>>(cand, ccnt, ovcnt, ovf, qGr, q2,
                                       stored, aux4, out);
}

// Round 19
// 176.213 us; speedup vs baseline: 1.3465x; 1.0172x over previous
//
#include <hip/hip_runtime.h>
#include <stdint.h>

// Problem constants (fixed by the reference)
#define NQ 1024
#define NS 131072
#define DMM 2048
#define DCC 64
#define K_TOP 16
#define EPS_RES_F 1e-8f
#define EPS_SQRT_F 1e-12f
#define EPS_A 0.01f       // bf16 hi-only dot abs-error coeff (rigorous bound ~0.004)

#define NCH 128           // candidate chunks over N
#define CHR (NS / NCH)    // 1024 rows per chunk
#define OVCAP 65536       // global overflow list capacity (rare)
#define SLOTS 24          // per-(q,chunk) candidate slots
#define MTOT (NCH * SLOTS)        // 3072 entries per query
#define EPT (MTOT / 256)          // 12 entries per thread
#define SCAP 3328         // survivor capacity >= MTOT + ovf slack

typedef __attribute__((ext_vector_type(8))) short short8v;  // 8 x bf16
typedef __attribute__((ext_vector_type(4))) float f32x4;
typedef unsigned long long u64t;

__device__ __forceinline__ unsigned short f2bf(float x) {  // RNE f32->bf16
  unsigned u = __float_as_uint(x);
  unsigned r = (u + 0x7FFFu + ((u >> 16) & 1u)) >> 16;
  return (unsigned short)r;
}
// directed bf16 rounding for POSITIVE floats (bounds stay provable)
__device__ __forceinline__ unsigned bf16_down_pos(float x) {
  return __float_as_uint(x) >> 16;
}
__device__ __forceinline__ unsigned bf16_up_pos(float x) {
  const unsigned u = __float_as_uint(x);
  return (u >> 16) + ((u & 0xFFFFu) ? 1u : 0u);
}

__device__ __forceinline__ void gl_lds16(const void* g, void* l) {
  __builtin_amdgcn_global_load_lds(
      (const __attribute__((address_space(1))) unsigned int*)g,
      (__attribute__((address_space(3))) unsigned int*)l, 16, 0, 0);
}

// exact key chain — MUST stay bit-identical to sub_kernel's accumulation
__device__ __forceinline__ float exact_key(const float* __restrict__ stored,
                                           const float* qgl, float q2v,
                                           const float4* __restrict__ aux4, int n) {
  const float4* srow = reinterpret_cast<const float4*>(stored + (size_t)n * DCC);
  float a = 0.f;
#pragma unroll
  for (int kb = 0; kb < 16; ++kb) {
    const float4 qv = *reinterpret_cast<const float4*>(&qgl[4 * kb]);
    const float4 sv = srow[kb];
    a = fmaf(qv.w, sv.w, fmaf(qv.z, sv.z, fmaf(qv.y, sv.y, fmaf(qv.x, sv.x, a))));
  }
  const float4 av = aux4[n];
  const float d2 = fmaf(-2.f, a, q2v + av.x);
  return (fmaxf(d2, 0.f) + EPS_SQRT_F) * av.w;
}

// All lanes of a wave: find the bin containing 0-based `rank` in hist[256]
__device__ __forceinline__ void bin_rank256(const int* hist, int rank, int lane,
                                            int& binOut, int& baseOut, int& totalOut) {
  const int b0 = hist[4 * lane + 0], b1 = hist[4 * lane + 1];
  const int b2 = hist[4 * lane + 2], b3 = hist[4 * lane + 3];
  const int s01 = b0 + b1, s012 = s01 + b2;
  const int s = s012 + b3;
  int inc = s;
#pragma unroll
  for (int off = 1; off < 64; off <<= 1) {
    const int u = __shfl_up(inc, off);
    if (lane >= off) inc += u;
  }
  totalOut = __shfl(inc, 63);
  const int excl = inc - s;
  const bool has = (excl <= rank) && (rank < inc);
  const unsigned long long mask = __ballot(has);
  if (mask == 0ULL) { binOut = -1; baseOut = 0; return; }
  const int who = __ffsll((unsigned long long)mask) - 1;
  const int exclW = __shfl(excl, who);
  const int c0 = __shfl(b0, who);
  const int c01 = __shfl(s01, who);
  const int c012 = __shfl(s012, who);
  const int r = rank - exclW;
  int sub, base;
  if (r < c0) { sub = 0; base = 0; }
  else if (r < c01) { sub = 1; base = c0; }
  else if (r < c012) { sub = 2; base = c01; }
  else { sub = 3; base = c012; }
  binOut = 4 * who + sub;
  baseOut = exclW + base;
}

// ---------------------------------------------------------------- G = M M^T
__global__ __launch_bounds__(256) void g_kernel(const float* __restrict__ M,
                                                float* __restrict__ G) {
  __shared__ __align__(16) float Ml[64 * 66];
  const int t = threadIdx.x;
  for (int p = 0; p < 16; ++p) {
    int i = p * 256 + t;
    Ml[(i >> 6) * 66 + (i & 63)] = M[i];
  }
  __syncthreads();
  const int e = blockIdx.x * 256 + t;
  const int i = e >> 6, j = e & 63;
  float a = 0.f;
#pragma unroll
  for (int k = 0; k < 64; ++k) a = fmaf(Ml[i * 66 + k], Ml[j * 66 + k], a);
  G[e] = a;
}

// ---- FUSED q+s kernel (r17 proven: -12us): blocks [0,256) q path,
// [256,2304) s path. Bodies BYTE-IDENTICAL to r9 frozen versions.
__global__ __launch_bounds__(256) void qs_kernel(
    const float* __restrict__ query, const float* __restrict__ W,
    const float* __restrict__ G, float* __restrict__ qGT,
    float* __restrict__ qGr, unsigned short* __restrict__ qGh,
    float* __restrict__ q2o, float* __restrict__ qeo,
    const float* __restrict__ stored, const float* __restrict__ resil,
    float4* __restrict__ aux4o, unsigned short* __restrict__ sho) {
  __shared__ __align__(16) char smem[50176];
  const int t = threadIdx.x;
  if (blockIdx.x < NQ / 4) {
    // ----------------- q path (r9 byte-identical) -----------------
    float (*qs)[DMM] = reinterpret_cast<float (*)[DMM]>(smem);            // 32768
    float (*part)[4][64] = reinterpret_cast<float (*)[4][64]>(smem + 32768); // 4096
    float (*qc)[64] = reinterpret_cast<float (*)[64]>(smem + 36864);      // 1024
    const int qb = blockIdx.x * 4;
    {
      const float4* src = reinterpret_cast<const float4*>(query + (size_t)qb * DMM);
      float4* dst = reinterpret_cast<float4*>(&qs[0][0]);
#pragma unroll
      for (int r = 0; r < 8; ++r) dst[r * 256 + t] = src[r * 256 + t];
    }
    __syncthreads();
    const int c = t & 63, seg = t >> 6;
    float p0 = 0.f, p1 = 0.f, p2 = 0.f, p3 = 0.f;
    const int kbase = seg * 512;
    for (int ki = 0; ki < 512; ++ki) {
      const int k = kbase + ki;
      const float w = W[(size_t)k * 64 + c];
      p0 = fmaf(qs[0][k], w, p0);
      p1 = fmaf(qs[1][k], w, p1);
      p2 = fmaf(qs[2][k], w, p2);
      p3 = fmaf(qs[3][k], w, p3);
    }
    part[0][seg][c] = p0; part[1][seg][c] = p1;
    part[2][seg][c] = p2; part[3][seg][c] = p3;
    __syncthreads();
    {
      const int q = t >> 6, cc = t & 63;
      qc[q][cc] = part[q][0][cc] + part[q][1][cc] + part[q][2][cc] + part[q][3][cc];
    }
    __syncthreads();
    const int w = t >> 6, lane = t & 63;
    float g = 0.f;
    for (int j = 0; j < 64; ++j) g = fmaf(qc[w][j], G[j * 64 + lane], g);
    const int q = qb + w;
    qGT[(size_t)lane * NQ + q] = g;
    qGr[(size_t)q * DCC + lane] = g;
    qGh[(size_t)q * DCC + lane] = f2bf(g);
    float pr = qc[w][lane] * g;
    float pn = g * g;
#pragma unroll
    for (int off = 32; off; off >>= 1) {
      pr += __shfl_xor(pr, off);
      pn += __shfl_xor(pn, off);
    }
    if (lane == 0) {
      q2o[q] = pr;
      qeo[q] = EPS_A * sqrtf(pn);
    }
  } else {
    // ----------------- s path (r9 byte-identical) -----------------
    float* Gl = reinterpret_cast<float*>(smem);               // 16896
    float* sst = reinterpret_cast<float*>(smem + 16896);      // 16384
    float* part2 = reinterpret_cast<float*>(smem + 33280);    // 8448
    float* ps = reinterpret_cast<float*>(smem + 41728);       // 8448
    const int nb = ((int)blockIdx.x - NQ / 4) * 64;
    for (int p = 0; p < 16; ++p) {
      int i = p * 256 + t;
      Gl[(i >> 6) * 66 + (i & 63)] = G[i];
    }
    {
      const float4* src = reinterpret_cast<const float4*>(stored + (size_t)nb * DCC);
      float4* dst = reinterpret_cast<float4*>(sst);
#pragma unroll
      for (int r = 0; r < 4; ++r) dst[r * 256 + t] = src[r * 256 + t];
    }
    __syncthreads();
    const int l = t & 31, tw = t >> 5;
    float acc0[8], acc1[8];
#pragma unroll
    for (int i = 0; i < 8; ++i) { acc0[i] = 0.f; acc1[i] = 0.f; }
    for (int kb = 0; kb < 16; ++kb) {
      const float2 ga0 = *reinterpret_cast<const float2*>(&Gl[(4 * kb + 0) * 66 + 2 * l]);
      const float2 ga1 = *reinterpret_cast<const float2*>(&Gl[(4 * kb + 1) * 66 + 2 * l]);
      const float2 ga2 = *reinterpret_cast<const float2*>(&Gl[(4 * kb + 2) * 66 + 2 * l]);
      const float2 ga3 = *reinterpret_cast<const float2*>(&Gl[(4 * kb + 3) * 66 + 2 * l]);
#pragma unroll
      for (int i = 0; i < 8; ++i) {
        const float4 sv = *reinterpret_cast<const float4*>(&sst[(8 * tw + i) * 64 + 4 * kb]);
        acc0[i] = fmaf(ga3.x, sv.w, fmaf(ga2.x, sv.z, fmaf(ga1.x, sv.y, fmaf(ga0.x, sv.x, acc0[i]))));
        acc1[i] = fmaf(ga3.y, sv.w, fmaf(ga2.y, sv.z, fmaf(ga1.y, sv.y, fmaf(ga0.y, sv.x, acc1[i]))));
      }
    }
#pragma unroll
    for (int i = 0; i < 8; ++i) {
      const int n = 8 * tw + i;
      const float2 sj = *reinterpret_cast<const float2*>(&sst[n * 64 + 2 * l]);
      part2[n * 33 + l] = acc0[i] * sj.x + acc1[i] * sj.y;
      ps[n * 33 + l] = sj.x * sj.x + sj.y * sj.y;
    }
    __syncthreads();
    for (int p = 0; p < 16; ++p) {
      const int i = p * 256 + t;
      const int nl = i >> 6, k = i & 63;
      sho[(size_t)(nb + nl) * DCC + k] = f2bf(sst[nl * 64 + k]);
    }
    if (t < 64) {
      float s = 0.f, sp = 0.f;
#pragma unroll
      for (int u = 0; u < 32; ++u) { s += part2[t * 33 + u]; sp += ps[t * 33 + u]; }
      const float rv = resil[nb + t] + EPS_RES_F;
      const float inv = 1.0f / rv;
      aux4o[nb + t] = make_float4(s, 0.5f * rv * rv, sqrtf(sp), inv * inv);
    }
  }
}

// --------- exact f32 keys for the 1/64 subsample (rows n = 64*j, j<2048)
__global__ __launch_bounds__(256) void sub_kernel(
    const float* __restrict__ stored, const float* __restrict__ qGT,
    const float* __restrict__ q2g, const float4* __restrict__ aux4,
    float* __restrict__ skeys) {
  __shared__ __align__(16) float qg[64 * 128];
  __shared__ __align__(16) float sst[64 * 64];
  __shared__ float s2sub[64];
  __shared__ float ir2sub[64];
  const int t = threadIdx.x;
  const int jb = blockIdx.x * 64;
  const int qbase = blockIdx.y * 128;
  for (int p = 0; p < 32; ++p) {
    const int i = p * 256 + t;
    const int k = i >> 7, qq = i & 127;
    qg[k * 128 + qq] = qGT[(size_t)k * NQ + qbase + qq];
  }
#pragma unroll
  for (int p = 0; p < 4; ++p) {
    const int idx = p * 256 + t;
    const int r = idx >> 4, f4 = idx & 15;
    reinterpret_cast<float4*>(sst)[r * 16 + f4] =
        reinterpret_cast<const float4*>(stored + (size_t)(64 * (jb + r)) * DCC)[f4];
  }
  if (t < 64) {
    const float4 v = aux4[64 * (jb + t)];
    s2sub[t] = v.x;
    ir2sub[t] = v.w;
  }
  __syncthreads();
  const int l = t & 31, tw = t >> 5;
  const int q0 = 4 * l;
  float q2r[4];
#pragma unroll
  for (int qq = 0; qq < 4; ++qq) q2r[qq] = q2g[qbase + q0 + qq];
  float acc[4][8];
#pragma unroll
  for (int qq = 0; qq < 4; ++qq)
#pragma unroll
    for (int i = 0; i < 8; ++i) acc[qq][i] = 0.f;
  for (int kb = 0; kb < 16; ++kb) {
    const float4 qa0 = *reinterpret_cast<const float4*>(&qg[(4 * kb + 0) * 128 + q0]);
    const float4 qa1 = *reinterpret_cast<const float4*>(&qg[(4 * kb + 1) * 128 + q0]);
    const float4 qa2 = *reinterpret_cast<const float4*>(&qg[(4 * kb + 2) * 128 + q0]);
    const float4 qa3 = *reinterpret_cast<const float4*>(&qg[(4 * kb + 3) * 128 + q0]);
#pragma unroll
    for (int i = 0; i < 8; ++i) {
      const float4 sv = *reinterpret_cast<const float4*>(&sst[(8 * tw + i) * 64 + 4 * kb]);
      acc[0][i] = fmaf(qa3.x, sv.w, fmaf(qa2.x, sv.z, fmaf(qa1.x, sv.y, fmaf(qa0.x, sv.x, acc[0][i]))));
      acc[1][i] = fmaf(qa3.y, sv.w, fmaf(qa2.y, sv.z, fmaf(qa1.y, sv.y, fmaf(qa0.y, sv.x, acc[1][i]))));
      acc[2][i] = fmaf(qa3.z, sv.w, fmaf(qa2.z, sv.z, fmaf(qa1.z, sv.y, fmaf(qa0.z, sv.x, acc[2][i]))));
      acc[3][i] = fmaf(qa3.w, sv.w, fmaf(qa2.w, sv.z, fmaf(qa1.w, sv.y, fmaf(qa0.w, sv.x, acc[3][i]))));
    }
  }
#pragma unroll
  for (int i = 0; i < 8; ++i) {
    const int jl = 8 * tw + i;
    const float s2v = s2sub[jl];
    const float ir2v = ir2sub[jl];
#pragma unroll
    for (int qq = 0; qq < 4; ++qq) {
      const float d2 = fmaf(-2.f, acc[qq][i], q2r[qq] + s2v);
      const float key = (fmaxf(d2, 0.f) + EPS_SQRT_F) * ir2v;
      skeys[(size_t)(qbase + q0 + qq) * 2048 + jb + jl] = key;
    }
  }
}

// ---- tau[q] = 16th smallest subsample key (exact), *1.0001 margin
__global__ __launch_bounds__(256) void tau_select(
    const float* __restrict__ skeys, float* __restrict__ tau) {
  __shared__ float lk[256 * 17];
  __shared__ float wkv[4][16];
  const int t = threadIdx.x;
  const int lane = t & 63, w = t >> 6;
  const int q = blockIdx.x;
  float k16[16];
#pragma unroll
  for (int s = 0; s < 16; ++s) k16[s] = 3.0e38f;
  for (int i = t; i < 2048; i += 256) {
    const float key = skeys[(size_t)q * 2048 + i];
    if (key < k16[15]) {
#pragma unroll
      for (int s = 15; s >= 1; --s) {
        const bool dprev = key < k16[s - 1];
        const float nk = dprev ? k16[s - 1] : key;
        if (key < k16[s]) k16[s] = nk;
      }
      if (key < k16[0]) k16[0] = key;
    }
  }
#pragma unroll
  for (int s = 0; s < 16; ++s) lk[t * 17 + s] = k16[s];
  __syncthreads();
  {
    int ptr = 0;
    for (int r = 0; r < K_TOP; ++r) {
      float v = lk[t * 17 + ptr];
      int who = lane;
#pragma unroll
      for (int off = 32; off; off >>= 1) {
        const float ov = __shfl_xor(v, off);
        const int ow = __shfl_xor(who, off);
        if (ov < v || (ov == v && ow < who)) { v = ov; who = ow; }
      }
      if (lane == 0) wkv[w][r] = v;
      if (lane == who) ptr++;
    }
  }
  __syncthreads();
  if (w == 0) {
    float v = wkv[lane >> 4][lane & 15];
    float t16 = 0.f;
    for (int r = 0; r < K_TOP; ++r) {
      float mv = v;
      int who = lane;
#pragma unroll
      for (int off = 32; off; off >>= 1) {
        const float ov = __shfl_xor(mv, off);
        const int ow = __shfl_xor(who, off);
        if (ov < mv || (ov == mv && ow < who)) { mv = ov; who = ow; }
      }
      t16 = mv;
      if (lane == who) v = 3.0e38f;
    }
    if (lane == 0) tau[q] = t16 * 1.0001f;
  }
}

// --------------- MFMA screening pass: bf16-hi cross-GEMM + bounded filter
// r19: r18's 128n x 32q tile (56 total regs/wave: VGPR 40 + 16 acc) at
// __launch_bounds__(256,8): budget 512/8 = 64 >= 56 — fits WITHOUT spill
// (r13's spill was at ~96 regs; tile shrink re-opened this door).
// LDS 8 x 18.9KB = 151.5 <= 160KB. Spill sentinel: FETCH >> 100MB => revert.
// stores u64: [63:48] bf16-UP upper key, [47:32] bf16-DOWN lower key, [31:0] n
__global__ __launch_bounds__(256, 8) void main_mfma(
    const unsigned short* __restrict__ sh, const unsigned short* __restrict__ qGh,
    const float* __restrict__ q2g, const float* __restrict__ qeg,
    const float* __restrict__ taug, const float4* __restrict__ aux4,
    int* __restrict__ ccnt, int* __restrict__ ovcnt,
    unsigned int* __restrict__ ovf, u64t* __restrict__ cand) {
  __shared__ __align__(16) char smA[16384];    // 128 n-rows x 128B, XOR-swizzled
  __shared__ __align__(16) float4 auxl[128];   // per-row {s2,h,sn,ir2}
  __shared__ int cnt32[32];
  const int t = threadIdx.x;
  const int lane = t & 63, w = t >> 6;
  const int l15 = lane & 15, hi4 = (lane >> 4) << 2;
  const int chunk = blockIdx.x;    // 0..127 ; linear%8 == chunk%8 -> XCD pinned
  const int qbase = blockIdx.y * 32;
  const int sx = ((lane & 7) << 4) ^ ((lane >> 3) << 4);
  const int g16 = (lane >> 4) << 4;
  const int swz = (lane & 7) << 4;

  if (t < 32) cnt32[t] = 0;
  float q2h_r[2], tau_r[2], qe_r[2];
#pragma unroll
  for (int qi = 0; qi < 2; ++qi) {
    const int q = qbase + qi * 16 + l15;
    q2h_r[qi] = 0.5f * q2g[q];
    tau_r[qi] = taug[q];
    qe_r[qi] = qeg[q];
  }
  // hoisted B fragments (loop-invariant): bfr[kh][qi]
  short8v bfr[2][2];
#pragma unroll
  for (int kh = 0; kh < 2; ++kh)
#pragma unroll
    for (int qi = 0; qi < 2; ++qi)
      bfr[kh][qi] = *reinterpret_cast<const short8v*>(
          (const char*)qGh + (((size_t)(qbase + qi * 16 + l15)) << 7) + (kh << 6) + g16);
  const f32x4 z4 = {0.f, 0.f, 0.f, 0.f};

  for (int nt = 0; nt < 8; ++nt) {
    const int nb = chunk * CHR + nt * 128;
    __syncthreads();  // previous tile fully consumed
#pragma unroll
    for (int ii = 0; ii < 4; ++ii) {
      const int row = w * 32 + ii * 8 + (lane >> 3);
      gl_lds16((const char*)sh + (size_t)(nb + row) * 128 + sx,
               smA + w * 4096 + ii * 1024);
    }
    if (t < 128) auxl[t] = aux4[nb + t];
    __syncthreads();  // drains vmcnt (global_load_lds) + lds writes

    f32x4 acc[2][2];
#pragma unroll
    for (int kh = 0; kh < 2; ++kh) {
      const int kx = ((kh << 6) | g16) ^ swz;
#pragma unroll
      for (int ni = 0; ni < 2; ++ni) {
        const short8v af = *reinterpret_cast<const short8v*>(
            smA + ((w * 32 + ni * 16 + l15) << 7) + kx);
#pragma unroll
        for (int qi = 0; qi < 2; ++qi)
          acc[ni][qi] = (kh == 0)
              ? __builtin_amdgcn_mfma_f32_16x16x32_bf16(af, bfr[0][qi], z4, 0, 0, 0)
              : __builtin_amdgcn_mfma_f32_16x16x32_bf16(af, bfr[1][qi], acc[ni][qi], 0, 0, 0);
      }
    }
    // epilogue: C/D map col(q)=lane&15, row(n)=(lane>>4)*4+reg
#pragma unroll
    for (int ni = 0; ni < 2; ++ni) {
#pragma unroll
      for (int r = 0; r < 4; ++r) {
        const int nl = w * 32 + ni * 16 + hi4 + r;
        const float4 av = auxl[nl];  // {s2, h, sn, ir2}
#pragma unroll
        for (int qi = 0; qi < 2; ++qi) {
          const float a = acc[ni][qi][r];
          const float t1 = fmaf(0.5f, av.x, q2h_r[qi]);
          const float thr = fmaf(-qe_r[qi], av.z, fmaf(-tau_r[qi], av.y, t1));
          if (a >= thr) {
            const int ql = qi * 16 + l15;
            const int n = nb + nl;
            const float d2 = 2.0f * (t1 - a);
            const float keyp = (fmaxf(d2, 0.0f) + EPS_SQRT_F) * av.w;
            const float ev = fmaf(2.0f * qe_r[qi] * av.z, av.w, 1e-5f * keyp) * 1.0002f;
            const unsigned hiw = (bf16_up_pos(keyp + ev) << 16) |
                                 bf16_down_pos(fmaxf(keyp - ev, 0.0f));
            const u64t ce = ((u64t)hiw << 32) | (unsigned)n;
            const int pos = atomicAdd(&cnt32[ql], 1);   // LDS atomic (fast)
            if (pos < SLOTS) {
              cand[((size_t)((qbase + ql) * NCH + chunk)) * SLOTS + pos] = ce;
            } else {
              const int gp = atomicAdd(ovcnt, 1);        // global, rare
              if (gp < OVCAP) ovf[gp] = ((unsigned)(qbase + ql) << 17) | (unsigned)n;
            }
          }
        }
      }
    }
  }
  __syncthreads();
  if (t < 32) {
    int c = cnt32[t];
    if (c > SLOTS) c = SLOTS;
    ccnt[(size_t)(qbase + t) * NCH + chunk] = c;
  }
}

// ------ final: histogram-rank bracket prune + exact refine, 1 block / query
__global__ __launch_bounds__(256) void final_kernel(
    const u64t* __restrict__ cand, const int* __restrict__ ccnt,
    const int* __restrict__ ovcnt, const unsigned int* __restrict__ ovf,
    const float* __restrict__ qGr, const float* __restrict__ q2g,
    const float* __restrict__ stored, const float4* __restrict__ aux4,
    float* __restrict__ out) {
  __shared__ __align__(16) float qgl[64];
  __shared__ int ccl[NCH];
  __shared__ int hist[256];
  __shared__ int scnt;
  __shared__ unsigned int sidx[SCAP];
  __shared__ u64t wku[4][16];
  const int t = threadIdx.x;
  const int lane = t & 63, w = t >> 6;
  const int q = blockIdx.x;
  if (t < 64) qgl[t] = qGr[(size_t)q * DCC + t];
  if (t < NCH) ccl[t] = min(ccnt[(size_t)q * NCH + t], SLOTS);
  hist[t] = 0;
  if (t == 0) scnt = 0;
  __syncthreads();
  u64t ev[EPT];
  unsigned vmask = 0;
  {
    const u64t* base = cand + (size_t)q * NCH * SLOTS;
#pragma unroll
    for (int p = 0; p < EPT; ++p) {
      const int i = p * 256 + t;
      ev[p] = base[i];
      const int seg = i / SLOTS;
      const int j = i - seg * SLOTS;
      if (j < ccl[seg]) vmask |= 1u << p;
    }
  }
#pragma unroll
  for (int p = 0; p < EPT; ++p)
    if (vmask & (1u << p)) atomicAdd(&hist[(int)(ev[p] >> 56)], 1);
  __syncthreads();
  int B, baseB, total;
  bin_rank256(hist, K_TOP - 1, lane, B, baseB, total);
  unsigned U16bits = 0xFFFFu;
  __syncthreads();
  if (total >= K_TOP) {
    hist[t] = 0;
    __syncthreads();
#pragma unroll
    for (int p = 0; p < EPT; ++p)
      if ((vmask & (1u << p)) && (int)(ev[p] >> 56) == B)
        atomicAdd(&hist[(int)((ev[p] >> 48) & 0xFF)], 1);
    __syncthreads();
    int b2, dummy, tot2;
    bin_rank256(hist, K_TOP - 1 - baseB, lane, b2, dummy, tot2);
    U16bits = ((unsigned)B << 8) | (unsigned)b2;
  }
#pragma unroll
  for (int p = 0; p < EPT; ++p) {
    if ((vmask & (1u << p)) && ((unsigned)(ev[p] >> 32) & 0xFFFFu) <= U16bits) {
      const int pos = atomicAdd(&scnt, 1);
      if (pos < SCAP) sidx[pos] = (unsigned)ev[p];
    }
  }
  {
    int oc = *ovcnt;
    if (oc > OVCAP) oc = OVCAP;
    for (int i = t; i < oc; i += 256) {
      const unsigned pk = ovf[i];
      if ((int)(pk >> 17) == q) {
        const int pos = atomicAdd(&scnt, 1);
        if (pos < SCAP) sidx[pos] = pk & 0x1FFFFu;
      }
    }
  }
  __syncthreads();
  int sc = scnt;
  if (sc > SCAP) sc = SCAP;
  const float q2v = q2g[q];
  u64t k16u[16];
#pragma unroll
  for (int s = 0; s < 16; ++s) k16u[s] = ~0ULL;
  for (int i = t; i < sc; i += 256) {
    const int n = (int)sidx[i];
    const u64t pv =
        ((u64t)__float_as_uint(exact_key(stored, qgl, q2v, aux4, n)) << 32) | (unsigned)n;
    if (pv < k16u[15]) {
#pragma unroll
      for (int s = 15; s >= 1; --s) {
        const bool dprev = pv < k16u[s - 1];
        const u64t nk = dprev ? k16u[s - 1] : pv;
        if (pv < k16u[s]) k16u[s] = nk;
      }
      if (pv < k16u[0]) k16u[0] = pv;
    }
  }
  {
    int ptr = 0;
    for (int r = 0; r < K_TOP; ++r) {
      u64t v = k16u[ptr];
      int who = lane;
#pragma unroll
      for (int off = 32; off; off >>= 1) {
        const u64t ov = __shfl_xor(v, off);
        const int ol = __shfl_xor(who, off);
        if (ov < v || (ov == v && ol < who)) { v = ov; who = ol; }
      }
      if (lane == 0) wku[w][r] = v;
      if (lane == who) ptr++;
    }
  }
  __syncthreads();
  if (w == 0) {
    u64t e = wku[lane >> 4][lane & 15];
    for (int r = 0; r < K_TOP; ++r) {
      u64t mv = e;
      int who = lane;
#pragma unroll
      for (int off = 32; off; off >>= 1) {
        const u64t ov = __shfl_xor(mv, off);
        const int ol = __shfl_xor(who, off);
        if (ov < mv || (ov == mv && ol < who)) { mv = ov; who = ol; }
      }
      if (lane == 0) {
        out[q * K_TOP + r] = sqrtf(__uint_as_float((unsigned)(mv >> 32)));
        out[NQ * K_TOP + q * K_TOP + r] = (float)(unsigned)(mv & 0xFFFFFFFFu);
      }
      if (lane == who) e = ~0ULL;
    }
  }
}

// ----------------------------------------------------------------- launcher
extern "C" void kernel_launch(void* const* d_in, const int* in_sizes, int n_in,
                              void* d_out, int out_size, void* d_ws, size_t ws_size,
                              hipStream_t stream) {
  const float* query  = (const float*)d_in[0];
  const float* stored = (const float*)d_in[1];
  const float* resil  = (const float*)d_in[2];
  const float* W      = (const float*)d_in[3];
  const float* M      = (const float*)d_in[4];

  char* ws = (char*)d_ws;
  size_t off = 0;
  float* G    = (float*)(ws + off); off += 16384;
  float* qGT  = (float*)(ws + off); off += 262144;   // [64][1024] f32
  float* qGr  = (float*)(ws + off); off += 262144;   // [1024][64] f32
  unsigned short* qGh = (unsigned short*)(ws + off); off += 131072;  // bf16
  float* q2   = (float*)(ws + off); off += 4096;
  float* qe   = (float*)(ws + off); off += 4096;
  float* tau  = (float*)(ws + off); off += 4096;
  float4* aux4 = (float4*)(ws + off); off += (size_t)NS * 16;  // 2 MB
  int*   ccnt = (int*)(ws + off);   off += (size_t)NQ * NCH * 4;  // 512 KB
  int*   ovcnt = (int*)(ws + off);  off += 4096;
  unsigned int* ovf = (unsigned int*)(ws + off); off += OVCAP * 4;  // 256 KB
  unsigned short* sh = (unsigned short*)(ws + off); off += 16777216;  // bf16 rows
  u64t* cand = (u64t*)(ws + off);   // [NQ][NCH][SLOTS] u64 = 24 MB
  float* skeys = (float*)cand;      // overlay (first 8 MB, used before cand)

  float* out = (float*)d_out;

  hipMemsetAsync(ovcnt, 0, 4096, stream);
  g_kernel<<<16, 256, 0, stream>>>(M, G);
  qs_kernel<<<NQ / 4 + NS / 64, 256, 0, stream>>>(query, W, G, qGT, qGr, qGh,
                                                  q2, qe, stored, resil, aux4, sh);
  sub_kernel<<<dim3(32, 8), 256, 0, stream>>>(stored, qGT, q2, aux4, skeys);
  tau_select<<<NQ, 256, 0, stream>>>(skeys, tau);
  main_mfma<<<dim3(NCH, NQ / 32), 256, 0, stream>>>(sh, qGh, q2, qe, tau, aux4,
                                                    ccnt, ovcnt, ovf, cand);
  final_kernel<<<NQ, 256, 0, stream>>>(cand, ccnt, ovcnt, ovf, qGr, q2,
                                       stored, aux4, out);
}